// Round 14
// baseline (1426.786 us; speedup 1.0000x reference)
//
#include <hip/hip_runtime.h>
#include <math.h>

#define NN 50000
#define HH 256
#define FIN 128
#define CC 112
#define LL 8
#define EE 800000
#define EPSB 1e-5f
#define NGRP 8
#define NPG (NN / NGRP)     // 6250 nodes per XCD-group
#define SLW 32              // spmm column-slice width (u16 -> 64 B/row = 1 line)
#define NSL (HH / SLW)      // 8 slices, one per XCD

typedef unsigned short u16;
typedef unsigned int u32;
typedef __attribute__((ext_vector_type(8))) short bf16x8;
typedef __attribute__((ext_vector_type(4))) float f32x4;
// clang ext vector (NOT HIP_vector_type class) — required by __builtin_nontemporal_*
typedef __attribute__((ext_vector_type(4))) unsigned int u32x4;

__device__ __forceinline__ u16 f2bf(float f) {
    u32 u = __float_as_uint(f);
    u32 r = (u + 0x7FFFu + ((u >> 16) & 1u)) >> 16;   // RNE
    return (u16)r;
}
__device__ __forceinline__ float bflo(u32 u) { return __uint_as_float(u << 16); }
__device__ __forceinline__ float bfhi(u32 u) { return __uint_as_float(u & 0xFFFF0000u); }
__device__ __forceinline__ float bf1(u16 u) { return __uint_as_float(((u32)u) << 16); }

__device__ __forceinline__ void gload16(const u16* g, u16* l) {
    __builtin_amdgcn_global_load_lds(
        (const __attribute__((address_space(1))) void*)g,
        (__attribute__((address_space(3))) void*)l, 16, 0, 0);
}

// ---------------- padded CSR build, XCD-partitioned (round-1/5 best config) ----------------
__global__ __launch_bounds__(256) void k_fill2(const int* __restrict__ ed1,
                                               const int* __restrict__ ed2,
                                               int* __restrict__ cur,
                                               u16* __restrict__ src1p,
                                               u16* __restrict__ src2p) {
    const int g = blockIdx.x & 7;
    const int bg = blockIdx.x >> 3;
    const int nthr = (gridDim.x >> 3) * 256;
    const int tid = bg * 256 + threadIdx.x;
    const int lo = g * NPG;

    for (int e = tid; e < EE; e += nthr) {
        int c = ed1[e + EE];
        if ((u32)(c - lo) < (u32)NPG) {
            int pos = atomicAdd(&cur[c], 1);
            src1p[(c << 6) + pos] = (u16)ed1[e];
        }
    }
    for (int e = tid; e < EE; e += nthr) {
        int c = ed2[e + EE];
        if ((u32)(c - lo) < (u32)NPG) {
            int pos = atomicAdd(&cur[NN + c], 1);
            src2p[(c << 6) + pos] = (u16)ed2[e];
        }
    }
}

__global__ void k_dinv2(const int* __restrict__ deg, float* __restrict__ dinv1,
                        float* __restrict__ dinv2, int n) {
    int v = blockIdx.x * blockDim.x + threadIdx.x;
    if (v >= 2 * n) return;
    float* d = (v < n) ? dinv1 : dinv2;
    int vv = (v < n) ? v : v - n;
    d[vv] = rsqrtf((float)(deg[v] + 1));  // +1 self-loop
}

// ---------------- weight transpose + bf16 cast: W[K][N] f32 -> Wt[N][K] bf16 ----------------
__global__ void k_wt(const float* __restrict__ W, u16* __restrict__ Wt, int K, int N) {
    __shared__ u16 sm[32][33];
    const float* Wl = W + (size_t)blockIdx.z * K * N;
    u16* Wtl = Wt + (size_t)blockIdx.z * K * N;
    int k0 = blockIdx.y * 32, n0 = blockIdx.x * 32;
    int tx = threadIdx.x, ty = threadIdx.y;  // 32 x 8
#pragma unroll
    for (int r = 0; r < 32; r += 8)
        sm[ty + r][tx] = f2bf(Wl[(size_t)(k0 + ty + r) * N + n0 + tx]);
    __syncthreads();
#pragma unroll
    for (int r = 0; r < 32; r += 8)
        Wtl[(size_t)(n0 + ty + r) * K + k0 + tx] = sm[tx][ty + r];
}

// outW [H=256][C=112] f32 -> outWt [128][256] bf16 (rows >= C zero); pad bias to 128
__global__ void k_outwt(const float* __restrict__ outW, const float* __restrict__ outb,
                        u16* __restrict__ outWt, float* __restrict__ obb) {
    int idx = blockIdx.x * 256 + threadIdx.x;     // 128*256
    if (idx >= 128 * 256) return;
    int n = idx >> 8, k = idx & 255;
    float v = (n < CC) ? outW[(size_t)k * CC + n] : 0.f;
    outWt[(size_t)n * HH + k] = f2bf(v);
    if (idx < 128) obb[idx] = (idx < CC) ? outb[idx] : 0.f;
}

// ---------------- fp32 -> bf16 cast ----------------
__global__ void k_xcast(const float* __restrict__ x, u16* __restrict__ xb, int n4) {
    int i = blockIdx.x * blockDim.x + threadIdx.x;
    if (i >= n4) return;
    float4 v = ((const float4*)x)[i];
    ushort4 o;
    o.x = f2bf(v.x); o.y = f2bf(v.y); o.z = f2bf(v.z); o.w = f2bf(v.w);
    *(ushort4*)(xb + ((size_t)i << 2)) = o;
}

// ---- bf16 MFMA GEMM: C = A @ Bt^T + bias, per-row scale; XCD-aware m/n swizzle when SWIZ ---
// SLICED: store u16 C in column-sliced layout [Nc/32][M][32] for the L2-pinned spmm gather.
template <bool F32OUT, bool SWIZ, bool SLICED>
__global__ __launch_bounds__(256) void k_gemm_bf16(const u16* __restrict__ A,
                                                   const u16* __restrict__ Bt,
                                                   const float* __restrict__ bias,
                                                   const float* __restrict__ rowscale,
                                                   void* __restrict__ Cout,
                                                   int M, int Nc, int K) {
    int m0, n0;
    if (SWIZ) {
        int id = blockIdx.x;
        int g = id >> 4, r = id & 15;
        int m = g * 8 + (r & 7);
        if (m * 128 >= M) return;
        m0 = m * 128;
        n0 = (r >> 3) * 128;
    } else {
        m0 = blockIdx.x * 128;
        n0 = 0;
    }
    __shared__ u16 As[128 * 32];
    __shared__ u16 Bs[128 * 32];
    const int tid = threadIdx.x;
    const int w = tid >> 6, lane = tid & 63;
    const int wr = (w >> 1) * 64, wc = (w & 1) * 64;
    const int lm = lane & 15, lq = lane >> 4;

    f32x4 acc[4][4];
#pragma unroll
    for (int i = 0; i < 4; ++i)
#pragma unroll
        for (int j = 0; j < 4; ++j) acc[i][j] = (f32x4){0.f, 0.f, 0.f, 0.f};

    const int srow = w * 16 + (lane >> 2);
    const int scol = (lane & 3) * 8;

    for (int k0 = 0; k0 < K; k0 += 32) {
        int gm = m0 + srow;        if (gm >= M) gm = M - 1;
        gload16(A + (size_t)gm * K + k0 + scol, As + (size_t)(w * 64) * 8);
        int gm2 = m0 + 64 + srow;  if (gm2 >= M) gm2 = M - 1;
        gload16(A + (size_t)gm2 * K + k0 + scol, As + (size_t)(256 + w * 64) * 8);
        gload16(Bt + (size_t)(n0 + srow) * K + k0 + scol, Bs + (size_t)(w * 64) * 8);
        gload16(Bt + (size_t)(n0 + 64 + srow) * K + k0 + scol, Bs + (size_t)(256 + w * 64) * 8);
        __syncthreads();

        bf16x8 af[4], bfr[4];
#pragma unroll
        for (int i = 0; i < 4; ++i)
            af[i] = *(const bf16x8*)(As + (wr + i * 16 + lm) * 32 + lq * 8);
#pragma unroll
        for (int j = 0; j < 4; ++j)
            bfr[j] = *(const bf16x8*)(Bs + (wc + j * 16 + lm) * 32 + lq * 8);
#pragma unroll
        for (int i = 0; i < 4; ++i)
#pragma unroll
            for (int j = 0; j < 4; ++j)
                acc[i][j] = __builtin_amdgcn_mfma_f32_16x16x32_bf16(af[i], bfr[j], acc[i][j], 0, 0, 0);
        __syncthreads();
    }

    // epilogue: C/D layout col=lane&15, row=(lane>>4)*4+reg  [m89-verified]
#pragma unroll
    for (int j = 0; j < 4; ++j) {
        int gc = n0 + wc + j * 16 + lm;
        float bj = (gc < Nc) ? bias[gc] : 0.f;
#pragma unroll
        for (int i = 0; i < 4; ++i) {
#pragma unroll
            for (int r = 0; r < 4; ++r) {
                int gr = m0 + wr + i * 16 + lq * 4 + r;
                if (gr < M && gc < Nc) {
                    float rs = rowscale ? rowscale[gr] : 1.0f;
                    float val = (acc[i][j][r] + bj) * rs;
                    if (F32OUT)
                        ((float*)Cout)[(size_t)gr * Nc + gc] = val;
                    else if (SLICED)
                        ((u16*)Cout)[((size_t)(gc >> 5) * M + gr) * SLW + (gc & 31)] = f2bf(val);
                    else
                        ((u16*)Cout)[(size_t)gr * Nc + gc] = f2bf(val);
                }
            }
        }
    }
}

#define ACC8(b) { A[0] += bflo(b.x); A[1] += bfhi(b.x); A[2] += bflo(b.y); A[3] += bfhi(b.y); \
                  A[4] += bflo(b.z); A[5] += bfhi(b.z); A[6] += bflo(b.w); A[7] += bfhi(b.w); }

// -- column-sliced gather SpMM, 4-lane row-subgroups, NT streams + fused BN stats ------------
// slice = blockIdx & 7 -> pinned to one XCD (grid 3128 % 8 == 0).
// Working-set arithmetic: per XCD = tb slice 3.2 MB (REUSED ~16x) + srcp index stream
// 6.4 MB (once) + hpre write-allocate 3.2 MB (no reuse) >> 4 MB L2 -> streams evict the
// reused slice (FETCH 88 vs 77 MB structural). Fix: NT-mark both streams (via clang
// ext_vector u32x4 — HIP uint4 is a class and rejected by the builtin, round-13 lesson).
__global__ __launch_bounds__(512) void k_spmm_sl4(const u16* __restrict__ ts,
                                                  const int* __restrict__ deg,
                                                  const u16* __restrict__ srcp,
                                                  const float* __restrict__ dinv,
                                                  u16* __restrict__ hpre,
                                                  float* __restrict__ bns,   // [8][HH]
                                                  float* __restrict__ bnq) { // [8][HH]
    __shared__ float lsum[8][SLW];
    __shared__ float lsq[8][SLW];
    const int s = blockIdx.x & 7;
    const int nb = blockIdx.x >> 3;
    const int w = threadIdx.x >> 6;
    const int lane = threadIdx.x & 63;
    const int sub = lane >> 2;          // node subgroup 0..15
    const int li = lane & 3;            // lane covers cols 8li..8li+7 of the slice (uint4)
    const u16* tsl = ts + (size_t)s * NN * SLW + li * 8;

    const int v = nb * 128 + w * 16 + sub;
    float ss[8], qq[8];
#pragma unroll
    for (int k = 0; k < 8; ++k) { ss[k] = 0.f; qq[k] = 0.f; }

    if (v < NN) {
        const u16* src = srcp + ((size_t)v << 6);
        const float dv = dinv[v];
        u32x4 a = *(const u32x4*)(tsl + (size_t)v * SLW);
        float A[8];
        A[0] = bflo(a.x); A[1] = bfhi(a.x); A[2] = bflo(a.y); A[3] = bfhi(a.y);
        A[4] = bflo(a.z); A[5] = bfhi(a.z); A[6] = bflo(a.w); A[7] = bfhi(a.w);
        int end = deg[v];
        int j = 0;
        for (; j + 8 <= end; j += 8) {
            u32x4 sp = __builtin_nontemporal_load((const u32x4*)(src + j));  // NT index stream
            u32x4 b0 = *(const u32x4*)(tsl + (size_t)(sp.x & 0xFFFFu) * SLW);
            u32x4 b1 = *(const u32x4*)(tsl + (size_t)(sp.x >> 16) * SLW);
            u32x4 b2 = *(const u32x4*)(tsl + (size_t)(sp.y & 0xFFFFu) * SLW);
            u32x4 b3 = *(const u32x4*)(tsl + (size_t)(sp.y >> 16) * SLW);
            u32x4 b4 = *(const u32x4*)(tsl + (size_t)(sp.z & 0xFFFFu) * SLW);
            u32x4 b5 = *(const u32x4*)(tsl + (size_t)(sp.z >> 16) * SLW);
            u32x4 b6 = *(const u32x4*)(tsl + (size_t)(sp.w & 0xFFFFu) * SLW);
            u32x4 b7 = *(const u32x4*)(tsl + (size_t)(sp.w >> 16) * SLW);
            ACC8(b0); ACC8(b1); ACC8(b2); ACC8(b3);
            ACC8(b4); ACC8(b5); ACC8(b6); ACC8(b7);
        }
        for (; j + 2 <= end; j += 2) {
            int s0 = __builtin_nontemporal_load(src + j);
            int s1 = __builtin_nontemporal_load(src + j + 1);
            u32x4 b0 = *(const u32x4*)(tsl + (size_t)s0 * SLW);
            u32x4 b1 = *(const u32x4*)(tsl + (size_t)s1 * SLW);
            ACC8(b0); ACC8(b1);
        }
        if (j < end) {
            int s0 = __builtin_nontemporal_load(src + j);
            u32x4 b0 = *(const u32x4*)(tsl + (size_t)s0 * SLW);
            ACC8(b0);
        }
        u32 p01 = (u32)f2bf(A[0] * dv) | ((u32)f2bf(A[1] * dv) << 16);
        u32 p23 = (u32)f2bf(A[2] * dv) | ((u32)f2bf(A[3] * dv) << 16);
        u32 p45 = (u32)f2bf(A[4] * dv) | ((u32)f2bf(A[5] * dv) << 16);
        u32 p67 = (u32)f2bf(A[6] * dv) | ((u32)f2bf(A[7] * dv) << 16);
        u32x4 ov; ov.x = p01; ov.y = p23; ov.z = p45; ov.w = p67;
        __builtin_nontemporal_store(ov, (u32x4*)(hpre + (size_t)v * HH + s * SLW + li * 8));
        ss[0] = bflo(p01); ss[1] = bfhi(p01); ss[2] = bflo(p23); ss[3] = bfhi(p23);
        ss[4] = bflo(p45); ss[5] = bfhi(p45); ss[6] = bflo(p67); ss[7] = bfhi(p67);
#pragma unroll
        for (int k = 0; k < 8; ++k) qq[k] = ss[k] * ss[k];
    }

    // reduce over the wave's 16 subgroups (lanes differing in bits 2..5)
#pragma unroll
    for (int d = 4; d < 64; d <<= 1) {
#pragma unroll
        for (int k = 0; k < 8; ++k) {
            ss[k] += __shfl_xor(ss[k], d, 64);
            qq[k] += __shfl_xor(qq[k], d, 64);
        }
    }
    if (lane < 4) {
#pragma unroll
        for (int k = 0; k < 8; ++k) { lsum[w][li * 8 + k] = ss[k]; lsq[w][li * 8 + k] = qq[k]; }
    }
    __syncthreads();
    int t = threadIdx.x;
    if (t < SLW) {
        float a = 0.f;
#pragma unroll
        for (int ww = 0; ww < 8; ++ww) a += lsum[ww][t];
        atomicAdd(&bns[(nb & 7) * HH + s * SLW + t], a);
    } else if (t < 2 * SLW) {
        int c = t - SLW;
        float a = 0.f;
#pragma unroll
        for (int ww = 0; ww < 8; ++ww) a += lsq[ww][c];
        atomicAdd(&bnq[(nb & 7) * HH + s * SLW + c], a);
    }
}

// ---- normalize + ReLU + weighted residual; bins folded once per block into LDS scale/shift -
__global__ __launch_bounds__(256) void k_bnnorm(const u16* __restrict__ hpre,
                         u16* __restrict__ accb, u16* __restrict__ hb,
                         const float* __restrict__ bins,   // [16][HH]: 8 sum + 8 sq
                         const float* __restrict__ gamma, const float* __restrict__ beta,
                         const float* __restrict__ wArr, int layer) {
    __shared__ float sscale[HH], sshift[HH];
    const float invN = 1.0f / (float)NN;
    {
        int tcol = threadIdx.x;
        float m = 0.f, qq = 0.f;
#pragma unroll
        for (int b = 0; b < 8; ++b) {
            m += bins[b * HH + tcol];
            qq += bins[(8 + b) * HH + tcol];
        }
        m *= invN;
        float var = qq * invN - m * m;
        float sc = rsqrtf(var + EPSB) * gamma[tcol];
        sscale[tcol] = sc;
        sshift[tcol] = beta[tcol] - m * sc;
    }
    __syncthreads();
    int idx = blockIdx.x * blockDim.x + threadIdx.x;
    if (idx >= NN * (HH / 4)) return;
    int c = (idx & 63) << 2;
    float w = wArr[layer];
    ushort4 hv = ((const ushort4*)hpre)[idx];
    ushort4 av = ((const ushort4*)accb)[idx];
    u16* hp = &hv.x;
    u16* ap = &av.x;
    ushort4 oh, oa;
    u16* ohp = &oh.x;
    u16* oap = &oa.x;
#pragma unroll
    for (int k = 0; k < 4; ++k) {
        float v = fmaf(bf1(hp[k]), sscale[c + k], sshift[c + k]);
        v = fmaxf(v, 0.f);
        oap[k] = f2bf(fmaf(w, v, bf1(ap[k])));
        ohp[k] = f2bf(v);
    }
    ((ushort4*)accb)[idx] = oa;
    *(ushort4*)(hb + ((size_t)idx << 2)) = oh;
}

// ---------------- softmax of the 8 layer weights ----------------
__global__ void k_softmaxw(const float* __restrict__ lw, float* __restrict__ wArr) {
    if (threadIdx.x == 0 && blockIdx.x == 0) {
        float m = -3.0e38f;
        for (int i = 0; i < LL; ++i) m = fmaxf(m, lw[i]);
        float e[LL]; float sum = 0.f;
        for (int i = 0; i < LL; ++i) { e[i] = expf(lw[i] - m); sum += e[i]; }
        for (int i = 0; i < LL; ++i) wArr[i] = e[i] / sum;
    }
}

// ---------------- log_softmax rows ----------------
__global__ __launch_bounds__(256) void k_logsoftmax(const float* __restrict__ z,
                                                    float* __restrict__ out) {
    int gt = blockIdx.x * blockDim.x + threadIdx.x;
    int v = gt >> 6;
    int lane = threadIdx.x & 63;
    if (v >= NN) return;
    const float* row = z + (size_t)v * CC;
    float v0 = row[lane];
    float v1 = (lane + 64 < CC) ? row[lane + 64] : -3.0e38f;
    float m = fmaxf(v0, v1);
#pragma unroll
    for (int d = 1; d < 64; d <<= 1) m = fmaxf(m, __shfl_xor(m, d, 64));
    float e = expf(v0 - m) + ((lane + 64 < CC) ? expf(v1 - m) : 0.f);
#pragma unroll
    for (int d = 1; d < 64; d <<= 1) e += __shfl_xor(e, d, 64);
    float lse = m + logf(e);
    out[(size_t)v * CC + lane] = v0 - lse;
    if (lane + 64 < CC) out[(size_t)v * CC + lane + 64] = v1 - lse;
}

extern "C" void kernel_launch(void* const* d_in, const int* in_sizes, int n_in,
                              void* d_out, int out_size, void* d_ws, size_t ws_size,
                              hipStream_t stream) {
    const float* x     = (const float*)d_in[0];
    const int*   e1    = (const int*)d_in[1];
    const int*   e2    = (const int*)d_in[2];
    const float* inW   = (const float*)d_in[3];
    const float* inb   = (const float*)d_in[4];
    const float* convW = (const float*)d_in[5];
    const float* convB = (const float*)d_in[6];
    const float* gamma = (const float*)d_in[7];
    const float* beta  = (const float*)d_in[8];
    const float* outW  = (const float*)d_in[9];
    const float* outb  = (const float*)d_in[10];
    const float* lw    = (const float*)d_in[11];

    char* ws = (char*)d_ws;
    size_t off = 0;
    auto alloc = [&](size_t bytes) -> void* {
        void* p = ws + off;
        off = (off + bytes + 255) & ~(size_t)255;
        return p;
    };
    u16*   hb    = (u16*)alloc((size_t)NN * HH * 2);     // bf16 h (GEMM A)
    u16*   tb    = (u16*)alloc((size_t)NN * HH * 2);     // bf16 t' SLICED [8][NN][32]; alias xb
    u16*   hpre  = (u16*)alloc((size_t)NN * HH * 2);     // spmm out; alias logits(f32)
    u16*   accb  = (u16*)alloc((size_t)NN * HH * 2);     // bf16 residual accumulator
    u16*   convWt= (u16*)alloc((size_t)LL * HH * HH * 2);
    u16*   inWt  = (u16*)alloc((size_t)HH * FIN * 2);
    u16*   outWt = (u16*)alloc((size_t)128 * HH * 2);
    float* obb   = (float*)alloc(128 * 4);
    float* dinv1 = (float*)alloc((size_t)NN * 4);
    float* dinv2 = (float*)alloc((size_t)NN * 4);
    u16*   src1p = (u16*)alloc((size_t)NN * 64 * 2);     // padded CSR, 64 u16 slots/node
    u16*   src2p = (u16*)alloc((size_t)NN * 64 * 2);
    int*   curz  = (int*)alloc((size_t)2 * NN * 4);      // cur1,cur2 (degree counters)
    float* bnsq  = (float*)alloc((size_t)LL * 16 * HH * 4);  // per layer: 8 sum + 8 sq bins
    float* wArr  = (float*)alloc(64);
    u16*   xb    = tb;            // x_bf16 dead once layer-0 conv GEMM writes tb
    float* logits = (float*)hpre; // fp32 logits: hpre free after last bnnorm

    int* cur1 = curz;

    hipMemsetAsync(curz, 0, (size_t)2 * NN * 4, stream);
    hipMemsetAsync(bnsq, 0, (size_t)LL * 16 * HH * 4, stream);
    hipMemsetAsync(accb, 0, (size_t)NN * HH * 2, stream);

    // padded CSR build: XCD-partitioned (8 groups x 256 blocks), u16 slots
    k_fill2<<<8 * 256, 256, 0, stream>>>(e1, e2, curz, src1p, src2p);
    k_dinv2<<<(2 * NN + 255) / 256, 256, 0, stream>>>(curz, dinv1, dinv2, NN);

    k_softmaxw<<<1, 64, 0, stream>>>(lw, wArr);

    // weight prep
    {
        dim3 g(HH / 32, HH / 32, LL);
        dim3 b(32, 8);
        k_wt<<<g, b, 0, stream>>>(convW, convWt, HH, HH);
        dim3 g2(HH / 32, FIN / 32, 1);
        k_wt<<<g2, b, 0, stream>>>(inW, inWt, FIN, HH);
        k_outwt<<<128, 256, 0, stream>>>(outW, outb, outWt, obb);
    }
    k_xcast<<<(NN * FIN / 4 + 255) / 256, 256, 0, stream>>>(x, xb, NN * FIN / 4);

    const int MT = (NN + 127) / 128;               // 391
    const int GSW = ((MT + 7) / 8) * 16;           // swizzled grid: 784
    // input FC: hb = bf16( x @ inW + inb )   (standard layout: next GEMM's A)
    k_gemm_bf16<false, true, false><<<GSW, 256, 0, stream>>>(xb, inWt, inb, nullptr, hb,
                                                             NN, HH, FIN);

    const int NBL = (NN + 127) / 128;              // 391 node-blocks (128 nodes each)
    const int SPB = NBL * NSL;                     // 391 x 8 slices = 3128 (% 8 == 0)
    const int ELB = (NN * (HH / 4) + 255) / 256;
    for (int i = 0; i < LL; ++i) {
        const int* dg = (i < LL / 2) ? cur1 : (curz + NN);
        const u16* sr = (i < LL / 2) ? src1p : src2p;
        const float* dv = (i < LL / 2) ? dinv1 : dinv2;
        float* bins = bnsq + (size_t)i * 16 * HH;
        // tb = bf16( dinv[r] * (hb @ convW_i + convB_i) )  in SLICED layout
        k_gemm_bf16<false, true, true><<<GSW, 256, 0, stream>>>(hb,
                                                          convWt + (size_t)i * HH * HH,
                                                          convB + (size_t)i * HH, dv, tb,
                                                          NN, HH, HH);
        k_spmm_sl4<<<SPB, 512, 0, stream>>>(tb, dg, sr, dv, hpre, bins, bins + 8 * HH);
        k_bnnorm<<<ELB, 256, 0, stream>>>(hpre, accb, hb, bins,
                                          gamma + (size_t)i * HH, beta + (size_t)i * HH,
                                          wArr, i);
    }

    // out FC: logits = accb @ outWt^T + obb   (fp32 store into hpre, Nc=112, single n-tile)
    k_gemm_bf16<true, false, false><<<MT, 256, 0, stream>>>(accb, outWt, obb, nullptr, logits,
                                                            NN, CC, HH);
    k_logsoftmax<<<NN / 4, 256, 0, stream>>>(logits, (float*)d_out);
}

// Round 15
// 1125.191 us; speedup vs baseline: 1.2680x; 1.2680x over previous
//
#include <hip/hip_runtime.h>
#include <math.h>

#define NN 50000
#define HH 256
#define FIN 128
#define CC 112
#define LL 8
#define EE 800000
#define EPSB 1e-5f
#define NGRP 8
#define NPG (NN / NGRP)     // 6250 nodes per XCD-group
#define SLW 32              // spmm column-slice width (u16 -> 64 B/row = 1 line)
#define NSL (HH / SLW)      // 8 slices, one per XCD

typedef unsigned short u16;
typedef unsigned int u32;
typedef __attribute__((ext_vector_type(8))) short bf16x8;
typedef __attribute__((ext_vector_type(4))) float f32x4;

__device__ __forceinline__ u16 f2bf(float f) {
    u32 u = __float_as_uint(f);
    u32 r = (u + 0x7FFFu + ((u >> 16) & 1u)) >> 16;   // RNE
    return (u16)r;
}
__device__ __forceinline__ float bflo(u32 u) { return __uint_as_float(u << 16); }
__device__ __forceinline__ float bfhi(u32 u) { return __uint_as_float(u & 0xFFFF0000u); }
__device__ __forceinline__ float bf1(u16 u) { return __uint_as_float(((u32)u) << 16); }

__device__ __forceinline__ void gload16(const u16* g, u16* l) {
    __builtin_amdgcn_global_load_lds(
        (const __attribute__((address_space(1))) void*)g,
        (__attribute__((address_space(3))) void*)l, 16, 0, 0);
}

// ---------------- padded CSR build, XCD-partitioned (round-1/5 best config) ----------------
__global__ __launch_bounds__(256) void k_fill2(const int* __restrict__ ed1,
                                               const int* __restrict__ ed2,
                                               int* __restrict__ cur,
                                               u16* __restrict__ src1p,
                                               u16* __restrict__ src2p) {
    const int g = blockIdx.x & 7;
    const int bg = blockIdx.x >> 3;
    const int nthr = (gridDim.x >> 3) * 256;
    const int tid = bg * 256 + threadIdx.x;
    const int lo = g * NPG;

    for (int e = tid; e < EE; e += nthr) {
        int c = ed1[e + EE];
        if ((u32)(c - lo) < (u32)NPG) {
            int pos = atomicAdd(&cur[c], 1);
            src1p[(c << 6) + pos] = (u16)ed1[e];
        }
    }
    for (int e = tid; e < EE; e += nthr) {
        int c = ed2[e + EE];
        if ((u32)(c - lo) < (u32)NPG) {
            int pos = atomicAdd(&cur[NN + c], 1);
            src2p[(c << 6) + pos] = (u16)ed2[e];
        }
    }
}

__global__ void k_dinv2(const int* __restrict__ deg, float* __restrict__ dinv1,
                        float* __restrict__ dinv2, int n) {
    int v = blockIdx.x * blockDim.x + threadIdx.x;
    if (v >= 2 * n) return;
    float* d = (v < n) ? dinv1 : dinv2;
    int vv = (v < n) ? v : v - n;
    d[vv] = rsqrtf((float)(deg[v] + 1));  // +1 self-loop
}

// ---------------- weight transpose + bf16 cast: W[K][N] f32 -> Wt[N][K] bf16 ----------------
__global__ void k_wt(const float* __restrict__ W, u16* __restrict__ Wt, int K, int N) {
    __shared__ u16 sm[32][33];
    const float* Wl = W + (size_t)blockIdx.z * K * N;
    u16* Wtl = Wt + (size_t)blockIdx.z * K * N;
    int k0 = blockIdx.y * 32, n0 = blockIdx.x * 32;
    int tx = threadIdx.x, ty = threadIdx.y;  // 32 x 8
#pragma unroll
    for (int r = 0; r < 32; r += 8)
        sm[ty + r][tx] = f2bf(Wl[(size_t)(k0 + ty + r) * N + n0 + tx]);
    __syncthreads();
#pragma unroll
    for (int r = 0; r < 32; r += 8)
        Wtl[(size_t)(n0 + ty + r) * K + k0 + tx] = sm[tx][ty + r];
}

// outW [H=256][C=112] f32 -> outWt [128][256] bf16 (rows >= C zero); pad bias to 128
__global__ void k_outwt(const float* __restrict__ outW, const float* __restrict__ outb,
                        u16* __restrict__ outWt, float* __restrict__ obb) {
    int idx = blockIdx.x * 256 + threadIdx.x;     // 128*256
    if (idx >= 128 * 256) return;
    int n = idx >> 8, k = idx & 255;
    float v = (n < CC) ? outW[(size_t)k * CC + n] : 0.f;
    outWt[(size_t)n * HH + k] = f2bf(v);
    if (idx < 128) obb[idx] = (idx < CC) ? outb[idx] : 0.f;
}

// ---------------- fp32 -> bf16 cast ----------------
__global__ void k_xcast(const float* __restrict__ x, u16* __restrict__ xb, int n4) {
    int i = blockIdx.x * blockDim.x + threadIdx.x;
    if (i >= n4) return;
    float4 v = ((const float4*)x)[i];
    ushort4 o;
    o.x = f2bf(v.x); o.y = f2bf(v.y); o.z = f2bf(v.z); o.w = f2bf(v.w);
    *(ushort4*)(xb + ((size_t)i << 2)) = o;
}

// ---- bf16 MFMA GEMM: C = A @ Bt^T + bias, per-row scale; XCD-aware m/n swizzle when SWIZ ---
// SLICED: store u16 C in column-sliced layout [Nc/32][M][32] for the L2-pinned spmm gather.
// LSM: fused log-softmax epilogue (out FC): block owns full 128x112 rows; row max/sum via
// LDS + 16-lane shfl; stores f32 log-probs directly, killing k_logsoftmax + logits traffic.
template <bool F32OUT, bool SWIZ, bool SLICED, bool LSM>
__global__ __launch_bounds__(256) void k_gemm_bf16(const u16* __restrict__ A,
                                                   const u16* __restrict__ Bt,
                                                   const float* __restrict__ bias,
                                                   const float* __restrict__ rowscale,
                                                   void* __restrict__ Cout,
                                                   int M, int Nc, int K) {
    int m0, n0;
    if (SWIZ) {
        int id = blockIdx.x;
        int g = id >> 4, r = id & 15;
        int m = g * 8 + (r & 7);
        if (m * 128 >= M) return;
        m0 = m * 128;
        n0 = (r >> 3) * 128;
    } else {
        m0 = blockIdx.x * 128;
        n0 = 0;
    }
    __shared__ u16 As[128 * 32];
    __shared__ u16 Bs[128 * 32];
    const int tid = threadIdx.x;
    const int w = tid >> 6, lane = tid & 63;
    const int wr = (w >> 1) * 64, wc = (w & 1) * 64;
    const int lm = lane & 15, lq = lane >> 4;

    f32x4 acc[4][4];
#pragma unroll
    for (int i = 0; i < 4; ++i)
#pragma unroll
        for (int j = 0; j < 4; ++j) acc[i][j] = (f32x4){0.f, 0.f, 0.f, 0.f};

    const int srow = w * 16 + (lane >> 2);
    const int scol = (lane & 3) * 8;

    for (int k0 = 0; k0 < K; k0 += 32) {
        int gm = m0 + srow;        if (gm >= M) gm = M - 1;
        gload16(A + (size_t)gm * K + k0 + scol, As + (size_t)(w * 64) * 8);
        int gm2 = m0 + 64 + srow;  if (gm2 >= M) gm2 = M - 1;
        gload16(A + (size_t)gm2 * K + k0 + scol, As + (size_t)(256 + w * 64) * 8);
        gload16(Bt + (size_t)(n0 + srow) * K + k0 + scol, Bs + (size_t)(w * 64) * 8);
        gload16(Bt + (size_t)(n0 + 64 + srow) * K + k0 + scol, Bs + (size_t)(256 + w * 64) * 8);
        __syncthreads();

        bf16x8 af[4], bfr[4];
#pragma unroll
        for (int i = 0; i < 4; ++i)
            af[i] = *(const bf16x8*)(As + (wr + i * 16 + lm) * 32 + lq * 8);
#pragma unroll
        for (int j = 0; j < 4; ++j)
            bfr[j] = *(const bf16x8*)(Bs + (wc + j * 16 + lm) * 32 + lq * 8);
#pragma unroll
        for (int i = 0; i < 4; ++i)
#pragma unroll
            for (int j = 0; j < 4; ++j)
                acc[i][j] = __builtin_amdgcn_mfma_f32_16x16x32_bf16(af[i], bfr[j], acc[i][j], 0, 0, 0);
        __syncthreads();
    }

    // epilogue: C/D layout col=lane&15, row=(lane>>4)*4+reg  [m89-verified]
    if (LSM) {
        __shared__ float smax[128][2];
        __shared__ float ssum[128][2];
        const int half = w & 1;
        float bj[4];
#pragma unroll
        for (int j = 0; j < 4; ++j) {
            int gc = wc + j * 16 + lm;
            bj[j] = (gc < Nc) ? bias[gc] : 0.f;
        }
        // pass 1: per-row max over this wave's valid cols, reduce over 16 lm-lanes
#pragma unroll
        for (int i = 0; i < 4; ++i) {
#pragma unroll
            for (int r = 0; r < 4; ++r) {
                float m = -3.0e38f;
#pragma unroll
                for (int j = 0; j < 4; ++j) {
                    int gc = wc + j * 16 + lm;
                    if (gc < Nc) m = fmaxf(m, acc[i][j][r] + bj[j]);
                }
#pragma unroll
                for (int d = 1; d < 16; d <<= 1) m = fmaxf(m, __shfl_xor(m, d, 64));
                if (lm == 0) smax[wr + i * 16 + lq * 4 + r][half] = m;
            }
        }
        __syncthreads();
        // pass 2: per-row sum of exp
#pragma unroll
        for (int i = 0; i < 4; ++i) {
#pragma unroll
            for (int r = 0; r < 4; ++r) {
                int row = wr + i * 16 + lq * 4 + r;
                float rm = fmaxf(smax[row][0], smax[row][1]);
                float s = 0.f;
#pragma unroll
                for (int j = 0; j < 4; ++j) {
                    int gc = wc + j * 16 + lm;
                    if (gc < Nc) s += expf(acc[i][j][r] + bj[j] - rm);
                }
#pragma unroll
                for (int d = 1; d < 16; d <<= 1) s += __shfl_xor(s, d, 64);
                if (lm == 0) ssum[row][half] = s;
            }
        }
        __syncthreads();
        // pass 3: store log-probs
#pragma unroll
        for (int i = 0; i < 4; ++i) {
#pragma unroll
            for (int r = 0; r < 4; ++r) {
                int row = wr + i * 16 + lq * 4 + r;
                int gr = m0 + row;
                if (gr < M) {
                    float rm = fmaxf(smax[row][0], smax[row][1]);
                    float lse = rm + logf(ssum[row][0] + ssum[row][1]);
#pragma unroll
                    for (int j = 0; j < 4; ++j) {
                        int gc = wc + j * 16 + lm;
                        if (gc < Nc)
                            ((float*)Cout)[(size_t)gr * Nc + gc] = acc[i][j][r] + bj[j] - lse;
                    }
                }
            }
        }
        return;
    }

#pragma unroll
    for (int j = 0; j < 4; ++j) {
        int gc = n0 + wc + j * 16 + lm;
        float bj = (gc < Nc) ? bias[gc] : 0.f;
#pragma unroll
        for (int i = 0; i < 4; ++i) {
#pragma unroll
            for (int r = 0; r < 4; ++r) {
                int gr = m0 + wr + i * 16 + lq * 4 + r;
                if (gr < M && gc < Nc) {
                    float rs = rowscale ? rowscale[gr] : 1.0f;
                    float val = (acc[i][j][r] + bj) * rs;
                    if (F32OUT)
                        ((float*)Cout)[(size_t)gr * Nc + gc] = val;
                    else if (SLICED)
                        ((u16*)Cout)[((size_t)(gc >> 5) * M + gr) * SLW + (gc & 31)] = f2bf(val);
                    else
                        ((u16*)Cout)[(size_t)gr * Nc + gc] = f2bf(val);
                }
            }
        }
    }
}

#define ACC8(b) { A[0] += bflo(b.x); A[1] += bfhi(b.x); A[2] += bflo(b.y); A[3] += bfhi(b.y); \
                  A[4] += bflo(b.z); A[5] += bfhi(b.z); A[6] += bflo(b.w); A[7] += bfhi(b.w); }

// -- column-sliced gather SpMM, 4-LANE row-subgroups (uint4 = 16 B/lane) + fused BN stats ----
// slice = blockIdx & 7 -> pinned to one XCD (grid 3128 % 8 == 0). Round-11 proven config
// (round-14 NT experiment REGRESSED 65->87 us: NT bypasses L2 entirely on gfx950 — reverted).
__global__ __launch_bounds__(512) void k_spmm_sl4(const u16* __restrict__ ts,
                                                  const int* __restrict__ deg,
                                                  const u16* __restrict__ srcp,
                                                  const float* __restrict__ dinv,
                                                  u16* __restrict__ hpre,
                                                  float* __restrict__ bns,   // [8][HH]
                                                  float* __restrict__ bnq) { // [8][HH]
    __shared__ float lsum[8][SLW];
    __shared__ float lsq[8][SLW];
    const int s = blockIdx.x & 7;
    const int nb = blockIdx.x >> 3;
    const int w = threadIdx.x >> 6;
    const int lane = threadIdx.x & 63;
    const int sub = lane >> 2;          // node subgroup 0..15
    const int li = lane & 3;            // lane covers cols 8li..8li+7 of the slice (uint4)
    const u16* tsl = ts + (size_t)s * NN * SLW + li * 8;

    const int v = nb * 128 + w * 16 + sub;
    float ss[8], qq[8];
#pragma unroll
    for (int k = 0; k < 8; ++k) { ss[k] = 0.f; qq[k] = 0.f; }

    if (v < NN) {
        const u16* src = srcp + ((size_t)v << 6);
        const float dv = dinv[v];
        uint4 a = *(const uint4*)(tsl + (size_t)v * SLW);
        float A[8];
        A[0] = bflo(a.x); A[1] = bfhi(a.x); A[2] = bflo(a.y); A[3] = bfhi(a.y);
        A[4] = bflo(a.z); A[5] = bfhi(a.z); A[6] = bflo(a.w); A[7] = bfhi(a.w);
        int end = deg[v];
        int j = 0;
        for (; j + 8 <= end; j += 8) {
            uint4 sp = *(const uint4*)(src + j);   // 8 packed u16 indices (subgroup-bcast)
            uint4 b0 = *(const uint4*)(tsl + (size_t)(sp.x & 0xFFFFu) * SLW);
            uint4 b1 = *(const uint4*)(tsl + (size_t)(sp.x >> 16) * SLW);
            uint4 b2 = *(const uint4*)(tsl + (size_t)(sp.y & 0xFFFFu) * SLW);
            uint4 b3 = *(const uint4*)(tsl + (size_t)(sp.y >> 16) * SLW);
            uint4 b4 = *(const uint4*)(tsl + (size_t)(sp.z & 0xFFFFu) * SLW);
            uint4 b5 = *(const uint4*)(tsl + (size_t)(sp.z >> 16) * SLW);
            uint4 b6 = *(const uint4*)(tsl + (size_t)(sp.w & 0xFFFFu) * SLW);
            uint4 b7 = *(const uint4*)(tsl + (size_t)(sp.w >> 16) * SLW);
            ACC8(b0); ACC8(b1); ACC8(b2); ACC8(b3);
            ACC8(b4); ACC8(b5); ACC8(b6); ACC8(b7);
        }
        for (; j + 2 <= end; j += 2) {
            int s0 = src[j], s1 = src[j + 1];
            uint4 b0 = *(const uint4*)(tsl + (size_t)s0 * SLW);
            uint4 b1 = *(const uint4*)(tsl + (size_t)s1 * SLW);
            ACC8(b0); ACC8(b1);
        }
        if (j < end) {
            uint4 b0 = *(const uint4*)(tsl + (size_t)src[j] * SLW);
            ACC8(b0);
        }
        u32 p01 = (u32)f2bf(A[0] * dv) | ((u32)f2bf(A[1] * dv) << 16);
        u32 p23 = (u32)f2bf(A[2] * dv) | ((u32)f2bf(A[3] * dv) << 16);
        u32 p45 = (u32)f2bf(A[4] * dv) | ((u32)f2bf(A[5] * dv) << 16);
        u32 p67 = (u32)f2bf(A[6] * dv) | ((u32)f2bf(A[7] * dv) << 16);
        uint4 ov; ov.x = p01; ov.y = p23; ov.z = p45; ov.w = p67;
        *(uint4*)(hpre + (size_t)v * HH + s * SLW + li * 8) = ov;
        ss[0] = bflo(p01); ss[1] = bfhi(p01); ss[2] = bflo(p23); ss[3] = bfhi(p23);
        ss[4] = bflo(p45); ss[5] = bfhi(p45); ss[6] = bflo(p67); ss[7] = bfhi(p67);
#pragma unroll
        for (int k = 0; k < 8; ++k) qq[k] = ss[k] * ss[k];
    }

    // reduce over the wave's 16 subgroups (lanes differing in bits 2..5)
#pragma unroll
    for (int d = 4; d < 64; d <<= 1) {
#pragma unroll
        for (int k = 0; k < 8; ++k) {
            ss[k] += __shfl_xor(ss[k], d, 64);
            qq[k] += __shfl_xor(qq[k], d, 64);
        }
    }
    if (lane < 4) {
#pragma unroll
        for (int k = 0; k < 8; ++k) { lsum[w][li * 8 + k] = ss[k]; lsq[w][li * 8 + k] = qq[k]; }
    }
    __syncthreads();
    int t = threadIdx.x;
    if (t < SLW) {
        float a = 0.f;
#pragma unroll
        for (int ww = 0; ww < 8; ++ww) a += lsum[ww][t];
        atomicAdd(&bns[(nb & 7) * HH + s * SLW + t], a);
    } else if (t < 2 * SLW) {
        int c = t - SLW;
        float a = 0.f;
#pragma unroll
        for (int ww = 0; ww < 8; ++ww) a += lsq[ww][c];
        atomicAdd(&bnq[(nb & 7) * HH + s * SLW + c], a);
    }
}

// ---- normalize + ReLU + weighted residual; bins folded once per block into LDS scale/shift -
// layer 0: accb is implicitly zero (skip read; also saves the accb memset).
// layer LL-1: hb is dead afterward (skip write).
__global__ __launch_bounds__(256) void k_bnnorm(const u16* __restrict__ hpre,
                         u16* __restrict__ accb, u16* __restrict__ hb,
                         const float* __restrict__ bins,   // [16][HH]: 8 sum + 8 sq
                         const float* __restrict__ gamma, const float* __restrict__ beta,
                         const float* __restrict__ wArr, int layer) {
    __shared__ float sscale[HH], sshift[HH];
    const float invN = 1.0f / (float)NN;
    {
        int tcol = threadIdx.x;
        float m = 0.f, qq = 0.f;
#pragma unroll
        for (int b = 0; b < 8; ++b) {
            m += bins[b * HH + tcol];
            qq += bins[(8 + b) * HH + tcol];
        }
        m *= invN;
        float var = qq * invN - m * m;
        float sc = rsqrtf(var + EPSB) * gamma[tcol];
        sscale[tcol] = sc;
        sshift[tcol] = beta[tcol] - m * sc;
    }
    __syncthreads();
    int idx = blockIdx.x * blockDim.x + threadIdx.x;
    if (idx >= NN * (HH / 4)) return;
    int c = (idx & 63) << 2;
    float w = wArr[layer];
    const bool first = (layer == 0);
    const bool last = (layer == LL - 1);
    ushort4 hv = ((const ushort4*)hpre)[idx];
    ushort4 av = make_ushort4(0, 0, 0, 0);
    if (!first) av = ((const ushort4*)accb)[idx];
    u16* hp = &hv.x;
    u16* ap = &av.x;
    ushort4 oh, oa;
    u16* ohp = &oh.x;
    u16* oap = &oa.x;
#pragma unroll
    for (int k = 0; k < 4; ++k) {
        float v = fmaf(bf1(hp[k]), sscale[c + k], sshift[c + k]);
        v = fmaxf(v, 0.f);
        oap[k] = f2bf(fmaf(w, v, bf1(ap[k])));
        ohp[k] = f2bf(v);
    }
    ((ushort4*)accb)[idx] = oa;
    if (!last) *(ushort4*)(hb + ((size_t)idx << 2)) = oh;
}

// ---------------- softmax of the 8 layer weights ----------------
__global__ void k_softmaxw(const float* __restrict__ lw, float* __restrict__ wArr) {
    if (threadIdx.x == 0 && blockIdx.x == 0) {
        float m = -3.0e38f;
        for (int i = 0; i < LL; ++i) m = fmaxf(m, lw[i]);
        float e[LL]; float sum = 0.f;
        for (int i = 0; i < LL; ++i) { e[i] = expf(lw[i] - m); sum += e[i]; }
        for (int i = 0; i < LL; ++i) wArr[i] = e[i] / sum;
    }
}

extern "C" void kernel_launch(void* const* d_in, const int* in_sizes, int n_in,
                              void* d_out, int out_size, void* d_ws, size_t ws_size,
                              hipStream_t stream) {
    const float* x     = (const float*)d_in[0];
    const int*   e1    = (const int*)d_in[1];
    const int*   e2    = (const int*)d_in[2];
    const float* inW   = (const float*)d_in[3];
    const float* inb   = (const float*)d_in[4];
    const float* convW = (const float*)d_in[5];
    const float* convB = (const float*)d_in[6];
    const float* gamma = (const float*)d_in[7];
    const float* beta  = (const float*)d_in[8];
    const float* outW  = (const float*)d_in[9];
    const float* outb  = (const float*)d_in[10];
    const float* lw    = (const float*)d_in[11];

    char* ws = (char*)d_ws;
    size_t off = 0;
    auto alloc = [&](size_t bytes) -> void* {
        void* p = ws + off;
        off = (off + bytes + 255) & ~(size_t)255;
        return p;
    };
    u16*   hb    = (u16*)alloc((size_t)NN * HH * 2);     // bf16 h (GEMM A)
    u16*   tb    = (u16*)alloc((size_t)NN * HH * 2);     // bf16 t' SLICED [8][NN][32]; alias xb
    u16*   hpre  = (u16*)alloc((size_t)NN * HH * 2);     // spmm out
    u16*   accb  = (u16*)alloc((size_t)NN * HH * 2);     // bf16 residual accumulator
    u16*   convWt= (u16*)alloc((size_t)LL * HH * HH * 2);
    u16*   inWt  = (u16*)alloc((size_t)HH * FIN * 2);
    u16*   outWt = (u16*)alloc((size_t)128 * HH * 2);
    float* obb   = (float*)alloc(128 * 4);
    float* dinv1 = (float*)alloc((size_t)NN * 4);
    float* dinv2 = (float*)alloc((size_t)NN * 4);
    u16*   src1p = (u16*)alloc((size_t)NN * 64 * 2);     // padded CSR, 64 u16 slots/node
    u16*   src2p = (u16*)alloc((size_t)NN * 64 * 2);
    int*   curz  = (int*)alloc((size_t)2 * NN * 4);      // cur1,cur2 (degree counters)
    float* bnsq  = (float*)alloc((size_t)LL * 16 * HH * 4);  // per layer: 8 sum + 8 sq bins
    float* wArr  = (float*)alloc(64);
    u16*   xb    = tb;            // x_bf16 dead once layer-0 conv GEMM writes tb

    int* cur1 = curz;

    hipMemsetAsync(curz, 0, (size_t)2 * NN * 4, stream);
    hipMemsetAsync(bnsq, 0, (size_t)LL * 16 * HH * 4, stream);

    // padded CSR build: XCD-partitioned (8 groups x 256 blocks), u16 slots
    k_fill2<<<8 * 256, 256, 0, stream>>>(e1, e2, curz, src1p, src2p);
    k_dinv2<<<(2 * NN + 255) / 256, 256, 0, stream>>>(curz, dinv1, dinv2, NN);

    k_softmaxw<<<1, 64, 0, stream>>>(lw, wArr);

    // weight prep
    {
        dim3 g(HH / 32, HH / 32, LL);
        dim3 b(32, 8);
        k_wt<<<g, b, 0, stream>>>(convW, convWt, HH, HH);
        dim3 g2(HH / 32, FIN / 32, 1);
        k_wt<<<g2, b, 0, stream>>>(inW, inWt, FIN, HH);
        k_outwt<<<128, 256, 0, stream>>>(outW, outb, outWt, obb);
    }
    k_xcast<<<(NN * FIN / 4 + 255) / 256, 256, 0, stream>>>(x, xb, NN * FIN / 4);

    const int MT = (NN + 127) / 128;               // 391
    const int GSW = ((MT + 7) / 8) * 16;           // swizzled grid: 784
    // input FC: hb = bf16( x @ inW + inb )   (standard layout: next GEMM's A)
    k_gemm_bf16<false, true, false, false><<<GSW, 256, 0, stream>>>(xb, inWt, inb, nullptr,
                                                                    hb, NN, HH, FIN);

    const int NBL = (NN + 127) / 128;              // 391 node-blocks (128 nodes each)
    const int SPB = NBL * NSL;                     // 391 x 8 slices = 3128 (% 8 == 0)
    const int ELB = (NN * (HH / 4) + 255) / 256;
    for (int i = 0; i < LL; ++i) {
        const int* dg = (i < LL / 2) ? cur1 : (curz + NN);
        const u16* sr = (i < LL / 2) ? src1p : src2p;
        const float* dv = (i < LL / 2) ? dinv1 : dinv2;
        float* bins = bnsq + (size_t)i * 16 * HH;
        // tb = bf16( dinv[r] * (hb @ convW_i + convB_i) )  in SLICED layout
        k_gemm_bf16<false, true, true, false><<<GSW, 256, 0, stream>>>(hb,
                                                          convWt + (size_t)i * HH * HH,
                                                          convB + (size_t)i * HH, dv, tb,
                                                          NN, HH, HH);
        k_spmm_sl4<<<SPB, 512, 0, stream>>>(tb, dg, sr, dv, hpre, bins, bins + 8 * HH);
        k_bnnorm<<<ELB, 256, 0, stream>>>(hpre, accb, hb, bins,
                                          gamma + (size_t)i * HH, beta + (size_t)i * HH,
                                          wArr, i);
    }

    // out FC fused with log-softmax: d_out = log_softmax(accb @ outWt^T + obb)
    k_gemm_bf16<true, false, false, true><<<MT, 256, 0, stream>>>(accb, outWt, obb, nullptr,
                                                                  (float*)d_out, NN, CC, HH);
}

// Round 16
// 1081.635 us; speedup vs baseline: 1.3191x; 1.0403x over previous
//
#include <hip/hip_runtime.h>
#include <math.h>

#define NN 50000
#define HH 256
#define FIN 128
#define CC 112
#define LL 8
#define EE 800000
#define EPSB 1e-5f
#define NGRP 8
#define NPG (NN / NGRP)     // 6250 nodes per XCD-group
#define SLW 32              // spmm column-slice width (u16 -> 64 B/row = 1 line)
#define NSL (HH / SLW)      // 8 slices, one per XCD
#define SROW (NN + 1)       // sliced tb rows per slice: node rows + zero sentinel row NN

typedef unsigned short u16;
typedef unsigned int u32;
typedef __attribute__((ext_vector_type(8))) short bf16x8;
typedef __attribute__((ext_vector_type(4))) float f32x4;

__device__ __forceinline__ u16 f2bf(float f) {
    u32 u = __float_as_uint(f);
    u32 r = (u + 0x7FFFu + ((u >> 16) & 1u)) >> 16;   // RNE
    return (u16)r;
}
__device__ __forceinline__ float bflo(u32 u) { return __uint_as_float(u << 16); }
__device__ __forceinline__ float bfhi(u32 u) { return __uint_as_float(u & 0xFFFF0000u); }
__device__ __forceinline__ float bf1(u16 u) { return __uint_as_float(((u32)u) << 16); }

__device__ __forceinline__ void gload16(const u16* g, u16* l) {
    __builtin_amdgcn_global_load_lds(
        (const __attribute__((address_space(1))) void*)g,
        (__attribute__((address_space(3))) void*)l, 16, 0, 0);
}

// ---------------- padded CSR build, XCD-partitioned (round-1/5 best config) ----------------
__global__ __launch_bounds__(256) void k_fill2(const int* __restrict__ ed1,
                                               const int* __restrict__ ed2,
                                               int* __restrict__ cur,
                                               u16* __restrict__ src1p,
                                               u16* __restrict__ src2p) {
    const int g = blockIdx.x & 7;
    const int bg = blockIdx.x >> 3;
    const int nthr = (gridDim.x >> 3) * 256;
    const int tid = bg * 256 + threadIdx.x;
    const int lo = g * NPG;

    for (int e = tid; e < EE; e += nthr) {
        int c = ed1[e + EE];
        if ((u32)(c - lo) < (u32)NPG) {
            int pos = atomicAdd(&cur[c], 1);
            src1p[(c << 6) + pos] = (u16)ed1[e];
        }
    }
    for (int e = tid; e < EE; e += nthr) {
        int c = ed2[e + EE];
        if ((u32)(c - lo) < (u32)NPG) {
            int pos = atomicAdd(&cur[NN + c], 1);
            src2p[(c << 6) + pos] = (u16)ed2[e];
        }
    }
}

// dinv + pad each srcp list to a multiple of 8 with the zero-row sentinel NN
// (removes all divergent tail loops from the spmm; pad fits: ceil(deg/8)*8 <= 64).
__global__ void k_dinv2(const int* __restrict__ deg, float* __restrict__ dinv1,
                        float* __restrict__ dinv2, u16* __restrict__ src1p,
                        u16* __restrict__ src2p, int n) {
    int v = blockIdx.x * blockDim.x + threadIdx.x;
    if (v >= 2 * n) return;
    int vv = (v < n) ? v : v - n;
    int dg = deg[v];
    ((v < n) ? dinv1 : dinv2)[vv] = rsqrtf((float)(dg + 1));  // +1 self-loop
    u16* sp = (v < n) ? src1p : src2p;
    int end8 = (dg + 7) & ~7;
    for (int j = dg; j < end8; ++j) sp[(vv << 6) + j] = (u16)NN;
}

// zero the sentinel row NN of each tb slice (runs AFTER input FC: pad rows alias xb region)
__global__ void k_zpad(u16* __restrict__ tb) {
    int t = threadIdx.x;            // 256 = 8 slices x 32 cols
    int s = t >> 5, c = t & 31;
    tb[((size_t)s * SROW + NN) * SLW + c] = 0;
}

// ---------------- weight transpose + bf16 cast: W[K][N] f32 -> Wt[N][K] bf16 ----------------
__global__ void k_wt(const float* __restrict__ W, u16* __restrict__ Wt, int K, int N) {
    __shared__ u16 sm[32][33];
    const float* Wl = W + (size_t)blockIdx.z * K * N;
    u16* Wtl = Wt + (size_t)blockIdx.z * K * N;
    int k0 = blockIdx.y * 32, n0 = blockIdx.x * 32;
    int tx = threadIdx.x, ty = threadIdx.y;  // 32 x 8
#pragma unroll
    for (int r = 0; r < 32; r += 8)
        sm[ty + r][tx] = f2bf(Wl[(size_t)(k0 + ty + r) * N + n0 + tx]);
    __syncthreads();
#pragma unroll
    for (int r = 0; r < 32; r += 8)
        Wtl[(size_t)(n0 + ty + r) * K + k0 + tx] = sm[tx][ty + r];
}

// outW [H=256][C=112] f32 -> outWt [128][256] bf16 (rows >= C zero); pad bias to 128
__global__ void k_outwt(const float* __restrict__ outW, const float* __restrict__ outb,
                        u16* __restrict__ outWt, float* __restrict__ obb) {
    int idx = blockIdx.x * 256 + threadIdx.x;     // 128*256
    if (idx >= 128 * 256) return;
    int n = idx >> 8, k = idx & 255;
    float v = (n < CC) ? outW[(size_t)k * CC + n] : 0.f;
    outWt[(size_t)n * HH + k] = f2bf(v);
    if (idx < 128) obb[idx] = (idx < CC) ? outb[idx] : 0.f;
}

// ---------------- fp32 -> bf16 cast ----------------
__global__ void k_xcast(const float* __restrict__ x, u16* __restrict__ xb, int n4) {
    int i = blockIdx.x * blockDim.x + threadIdx.x;
    if (i >= n4) return;
    float4 v = ((const float4*)x)[i];
    ushort4 o;
    o.x = f2bf(v.x); o.y = f2bf(v.y); o.z = f2bf(v.z); o.w = f2bf(v.w);
    *(ushort4*)(xb + ((size_t)i << 2)) = o;
}

// ---- bf16 MFMA GEMM: C = A @ Bt^T + bias, per-row scale; XCD-aware m/n swizzle when SWIZ ---
// SLICED: store u16 C in column-sliced layout [Nc/32][SROW][32] (stride M+1: sentinel row).
// LSM: fused log-softmax epilogue (out FC).
template <bool F32OUT, bool SWIZ, bool SLICED, bool LSM>
__global__ __launch_bounds__(256) void k_gemm_bf16(const u16* __restrict__ A,
                                                   const u16* __restrict__ Bt,
                                                   const float* __restrict__ bias,
                                                   const float* __restrict__ rowscale,
                                                   void* __restrict__ Cout,
                                                   int M, int Nc, int K) {
    int m0, n0;
    if (SWIZ) {
        int id = blockIdx.x;
        int g = id >> 4, r = id & 15;
        int m = g * 8 + (r & 7);
        if (m * 128 >= M) return;
        m0 = m * 128;
        n0 = (r >> 3) * 128;
    } else {
        m0 = blockIdx.x * 128;
        n0 = 0;
    }
    __shared__ u16 As[128 * 32];
    __shared__ u16 Bs[128 * 32];
    const int tid = threadIdx.x;
    const int w = tid >> 6, lane = tid & 63;
    const int wr = (w >> 1) * 64, wc = (w & 1) * 64;
    const int lm = lane & 15, lq = lane >> 4;

    f32x4 acc[4][4];
#pragma unroll
    for (int i = 0; i < 4; ++i)
#pragma unroll
        for (int j = 0; j < 4; ++j) acc[i][j] = (f32x4){0.f, 0.f, 0.f, 0.f};

    const int srow = w * 16 + (lane >> 2);
    const int scol = (lane & 3) * 8;

    for (int k0 = 0; k0 < K; k0 += 32) {
        int gm = m0 + srow;        if (gm >= M) gm = M - 1;
        gload16(A + (size_t)gm * K + k0 + scol, As + (size_t)(w * 64) * 8);
        int gm2 = m0 + 64 + srow;  if (gm2 >= M) gm2 = M - 1;
        gload16(A + (size_t)gm2 * K + k0 + scol, As + (size_t)(256 + w * 64) * 8);
        gload16(Bt + (size_t)(n0 + srow) * K + k0 + scol, Bs + (size_t)(w * 64) * 8);
        gload16(Bt + (size_t)(n0 + 64 + srow) * K + k0 + scol, Bs + (size_t)(256 + w * 64) * 8);
        __syncthreads();

        bf16x8 af[4], bfr[4];
#pragma unroll
        for (int i = 0; i < 4; ++i)
            af[i] = *(const bf16x8*)(As + (wr + i * 16 + lm) * 32 + lq * 8);
#pragma unroll
        for (int j = 0; j < 4; ++j)
            bfr[j] = *(const bf16x8*)(Bs + (wc + j * 16 + lm) * 32 + lq * 8);
#pragma unroll
        for (int i = 0; i < 4; ++i)
#pragma unroll
            for (int j = 0; j < 4; ++j)
                acc[i][j] = __builtin_amdgcn_mfma_f32_16x16x32_bf16(af[i], bfr[j], acc[i][j], 0, 0, 0);
        __syncthreads();
    }

    // epilogue: C/D layout col=lane&15, row=(lane>>4)*4+reg  [m89-verified]
    if (LSM) {
        __shared__ float smax[128][2];
        __shared__ float ssum[128][2];
        const int half = w & 1;
        float bj[4];
#pragma unroll
        for (int j = 0; j < 4; ++j) {
            int gc = wc + j * 16 + lm;
            bj[j] = (gc < Nc) ? bias[gc] : 0.f;
        }
#pragma unroll
        for (int i = 0; i < 4; ++i) {
#pragma unroll
            for (int r = 0; r < 4; ++r) {
                float m = -3.0e38f;
#pragma unroll
                for (int j = 0; j < 4; ++j) {
                    int gc = wc + j * 16 + lm;
                    if (gc < Nc) m = fmaxf(m, acc[i][j][r] + bj[j]);
                }
#pragma unroll
                for (int d = 1; d < 16; d <<= 1) m = fmaxf(m, __shfl_xor(m, d, 64));
                if (lm == 0) smax[wr + i * 16 + lq * 4 + r][half] = m;
            }
        }
        __syncthreads();
#pragma unroll
        for (int i = 0; i < 4; ++i) {
#pragma unroll
            for (int r = 0; r < 4; ++r) {
                int row = wr + i * 16 + lq * 4 + r;
                float rm = fmaxf(smax[row][0], smax[row][1]);
                float s = 0.f;
#pragma unroll
                for (int j = 0; j < 4; ++j) {
                    int gc = wc + j * 16 + lm;
                    if (gc < Nc) s += expf(acc[i][j][r] + bj[j] - rm);
                }
#pragma unroll
                for (int d = 1; d < 16; d <<= 1) s += __shfl_xor(s, d, 64);
                if (lm == 0) ssum[row][half] = s;
            }
        }
        __syncthreads();
#pragma unroll
        for (int i = 0; i < 4; ++i) {
#pragma unroll
            for (int r = 0; r < 4; ++r) {
                int row = wr + i * 16 + lq * 4 + r;
                int gr = m0 + row;
                if (gr < M) {
                    float rm = fmaxf(smax[row][0], smax[row][1]);
                    float lse = rm + logf(ssum[row][0] + ssum[row][1]);
#pragma unroll
                    for (int j = 0; j < 4; ++j) {
                        int gc = wc + j * 16 + lm;
                        if (gc < Nc)
                            ((float*)Cout)[(size_t)gr * Nc + gc] = acc[i][j][r] + bj[j] - lse;
                    }
                }
            }
        }
        return;
    }

#pragma unroll
    for (int j = 0; j < 4; ++j) {
        int gc = n0 + wc + j * 16 + lm;
        float bj = (gc < Nc) ? bias[gc] : 0.f;
#pragma unroll
        for (int i = 0; i < 4; ++i) {
#pragma unroll
            for (int r = 0; r < 4; ++r) {
                int gr = m0 + wr + i * 16 + lq * 4 + r;
                if (gr < M && gc < Nc) {
                    float rs = rowscale ? rowscale[gr] : 1.0f;
                    float val = (acc[i][j][r] + bj) * rs;
                    if (F32OUT)
                        ((float*)Cout)[(size_t)gr * Nc + gc] = val;
                    else if (SLICED)
                        ((u16*)Cout)[((size_t)(gc >> 5) * (M + 1) + gr) * SLW + (gc & 31)] = f2bf(val);
                    else
                        ((u16*)Cout)[(size_t)gr * Nc + gc] = f2bf(val);
                }
            }
        }
    }
}

#define ACC8(b) { A[0] += bflo(b.x); A[1] += bfhi(b.x); A[2] += bflo(b.y); A[3] += bfhi(b.y); \
                  A[4] += bflo(b.z); A[5] += bfhi(b.z); A[6] += bflo(b.w); A[7] += bfhi(b.w); }

// -- column-sliced gather SpMM, 4-lane row-subgroups, UNIFORM padded loop + fused BN stats ---
// slice = blockIdx & 7 -> pinned to one XCD (grid 3128 % 8 == 0). srcp lists are padded to
// multiples of 8 with sentinel NN (zero row) -> single uniform unroll-8 loop, no divergent
// tails, near-uniform trip counts across the wave's 16 subgroups.
__global__ __launch_bounds__(512) void k_spmm_sl4(const u16* __restrict__ ts,
                                                  const int* __restrict__ deg,
                                                  const u16* __restrict__ srcp,
                                                  const float* __restrict__ dinv,
                                                  u16* __restrict__ hpre,
                                                  float* __restrict__ bns,   // [8][HH]
                                                  float* __restrict__ bnq) { // [8][HH]
    __shared__ float lsum[8][SLW];
    __shared__ float lsq[8][SLW];
    const int s = blockIdx.x & 7;
    const int nb = blockIdx.x >> 3;
    const int w = threadIdx.x >> 6;
    const int lane = threadIdx.x & 63;
    const int sub = lane >> 2;          // node subgroup 0..15
    const int li = lane & 3;            // lane covers cols 8li..8li+7 of the slice (uint4)
    const u16* tsl = ts + (size_t)s * SROW * SLW + li * 8;

    const int v = nb * 128 + w * 16 + sub;
    float ss[8], qq[8];
#pragma unroll
    for (int k = 0; k < 8; ++k) { ss[k] = 0.f; qq[k] = 0.f; }

    if (v < NN) {
        const u16* src = srcp + ((size_t)v << 6);
        const float dv = dinv[v];
        uint4 a = *(const uint4*)(tsl + (size_t)v * SLW);
        float A[8];
        A[0] = bflo(a.x); A[1] = bfhi(a.x); A[2] = bflo(a.y); A[3] = bfhi(a.y);
        A[4] = bflo(a.z); A[5] = bfhi(a.z); A[6] = bflo(a.w); A[7] = bfhi(a.w);
        const int end = (deg[v] + 7) & ~7;       // padded: uniform 8-stride, no tails
        for (int j = 0; j < end; j += 8) {
            uint4 sp = *(const uint4*)(src + j);   // 8 packed u16 indices (subgroup-bcast)
            uint4 b0 = *(const uint4*)(tsl + (size_t)(sp.x & 0xFFFFu) * SLW);
            uint4 b1 = *(const uint4*)(tsl + (size_t)(sp.x >> 16) * SLW);
            uint4 b2 = *(const uint4*)(tsl + (size_t)(sp.y & 0xFFFFu) * SLW);
            uint4 b3 = *(const uint4*)(tsl + (size_t)(sp.y >> 16) * SLW);
            uint4 b4 = *(const uint4*)(tsl + (size_t)(sp.z & 0xFFFFu) * SLW);
            uint4 b5 = *(const uint4*)(tsl + (size_t)(sp.z >> 16) * SLW);
            uint4 b6 = *(const uint4*)(tsl + (size_t)(sp.w & 0xFFFFu) * SLW);
            uint4 b7 = *(const uint4*)(tsl + (size_t)(sp.w >> 16) * SLW);
            ACC8(b0); ACC8(b1); ACC8(b2); ACC8(b3);
            ACC8(b4); ACC8(b5); ACC8(b6); ACC8(b7);
        }
        u32 p01 = (u32)f2bf(A[0] * dv) | ((u32)f2bf(A[1] * dv) << 16);
        u32 p23 = (u32)f2bf(A[2] * dv) | ((u32)f2bf(A[3] * dv) << 16);
        u32 p45 = (u32)f2bf(A[4] * dv) | ((u32)f2bf(A[5] * dv) << 16);
        u32 p67 = (u32)f2bf(A[6] * dv) | ((u32)f2bf(A[7] * dv) << 16);
        uint4 ov; ov.x = p01; ov.y = p23; ov.z = p45; ov.w = p67;
        *(uint4*)(hpre + (size_t)v * HH + s * SLW + li * 8) = ov;
        ss[0] = bflo(p01); ss[1] = bfhi(p01); ss[2] = bflo(p23); ss[3] = bfhi(p23);
        ss[4] = bflo(p45); ss[5] = bfhi(p45); ss[6] = bflo(p67); ss[7] = bfhi(p67);
#pragma unroll
        for (int k = 0; k < 8; ++k) qq[k] = ss[k] * ss[k];
    }

    // reduce over the wave's 16 subgroups (lanes differing in bits 2..5)
#pragma unroll
    for (int d = 4; d < 64; d <<= 1) {
#pragma unroll
        for (int k = 0; k < 8; ++k) {
            ss[k] += __shfl_xor(ss[k], d, 64);
            qq[k] += __shfl_xor(qq[k], d, 64);
        }
    }
    if (lane < 4) {
#pragma unroll
        for (int k = 0; k < 8; ++k) { lsum[w][li * 8 + k] = ss[k]; lsq[w][li * 8 + k] = qq[k]; }
    }
    __syncthreads();
    int t = threadIdx.x;
    if (t < SLW) {
        float a = 0.f;
#pragma unroll
        for (int ww = 0; ww < 8; ++ww) a += lsum[ww][t];
        atomicAdd(&bns[(nb & 7) * HH + s * SLW + t], a);
    } else if (t < 2 * SLW) {
        int c = t - SLW;
        float a = 0.f;
#pragma unroll
        for (int ww = 0; ww < 8; ++ww) a += lsq[ww][c];
        atomicAdd(&bnq[(nb & 7) * HH + s * SLW + c], a);
    }
}

// ---- normalize + ReLU + weighted residual; bins folded once per block into LDS scale/shift -
// layer 0: accb implicitly zero (skip read; saves accb memset). layer LL-1: skip dead hb write.
__global__ __launch_bounds__(256) void k_bnnorm(const u16* __restrict__ hpre,
                         u16* __restrict__ accb, u16* __restrict__ hb,
                         const float* __restrict__ bins,   // [16][HH]: 8 sum + 8 sq
                         const float* __restrict__ gamma, const float* __restrict__ beta,
                         const float* __restrict__ wArr, int layer) {
    __shared__ float sscale[HH], sshift[HH];
    const float invN = 1.0f / (float)NN;
    {
        int tcol = threadIdx.x;
        float m = 0.f, qq = 0.f;
#pragma unroll
        for (int b = 0; b < 8; ++b) {
            m += bins[b * HH + tcol];
            qq += bins[(8 + b) * HH + tcol];
        }
        m *= invN;
        float var = qq * invN - m * m;
        float sc = rsqrtf(var + EPSB) * gamma[tcol];
        sscale[tcol] = sc;
        sshift[tcol] = beta[tcol] - m * sc;
    }
    __syncthreads();
    int idx = blockIdx.x * blockDim.x + threadIdx.x;
    if (idx >= NN * (HH / 4)) return;
    int c = (idx & 63) << 2;
    float w = wArr[layer];
    const bool first = (layer == 0);
    const bool last = (layer == LL - 1);
    ushort4 hv = ((const ushort4*)hpre)[idx];
    ushort4 av = make_ushort4(0, 0, 0, 0);
    if (!first) av = ((const ushort4*)accb)[idx];
    u16* hp = &hv.x;
    u16* ap = &av.x;
    ushort4 oh, oa;
    u16* ohp = &oh.x;
    u16* oap = &oa.x;
#pragma unroll
    for (int k = 0; k < 4; ++k) {
        float v = fmaf(bf1(hp[k]), sscale[c + k], sshift[c + k]);
        v = fmaxf(v, 0.f);
        oap[k] = f2bf(fmaf(w, v, bf1(ap[k])));
        ohp[k] = f2bf(v);
    }
    ((ushort4*)accb)[idx] = oa;
    if (!last) *(ushort4*)(hb + ((size_t)idx << 2)) = oh;
}

// ---------------- softmax of the 8 layer weights ----------------
__global__ void k_softmaxw(const float* __restrict__ lw, float* __restrict__ wArr) {
    if (threadIdx.x == 0 && blockIdx.x == 0) {
        float m = -3.0e38f;
        for (int i = 0; i < LL; ++i) m = fmaxf(m, lw[i]);
        float e[LL]; float sum = 0.f;
        for (int i = 0; i < LL; ++i) { e[i] = expf(lw[i] - m); sum += e[i]; }
        for (int i = 0; i < LL; ++i) wArr[i] = e[i] / sum;
    }
}

extern "C" void kernel_launch(void* const* d_in, const int* in_sizes, int n_in,
                              void* d_out, int out_size, void* d_ws, size_t ws_size,
                              hipStream_t stream) {
    const float* x     = (const float*)d_in[0];
    const int*   e1    = (const int*)d_in[1];
    const int*   e2    = (const int*)d_in[2];
    const float* inW   = (const float*)d_in[3];
    const float* inb   = (const float*)d_in[4];
    const float* convW = (const float*)d_in[5];
    const float* convB = (const float*)d_in[6];
    const float* gamma = (const float*)d_in[7];
    const float* beta  = (const float*)d_in[8];
    const float* outW  = (const float*)d_in[9];
    const float* outb  = (const float*)d_in[10];
    const float* lw    = (const float*)d_in[11];

    char* ws = (char*)d_ws;
    size_t off = 0;
    auto alloc = [&](size_t bytes) -> void* {
        void* p = ws + off;
        off = (off + bytes + 255) & ~(size_t)255;
        return p;
    };
    u16*   hb    = (u16*)alloc((size_t)NN * HH * 2);     // bf16 h (GEMM A)
    u16*   tb    = (u16*)alloc((size_t)SROW * HH * 2);   // bf16 t' SLICED [8][SROW][32]; alias xb
    u16*   hpre  = (u16*)alloc((size_t)NN * HH * 2);     // spmm out
    u16*   accb  = (u16*)alloc((size_t)NN * HH * 2);     // bf16 residual accumulator
    u16*   convWt= (u16*)alloc((size_t)LL * HH * HH * 2);
    u16*   inWt  = (u16*)alloc((size_t)HH * FIN * 2);
    u16*   outWt = (u16*)alloc((size_t)128 * HH * 2);
    float* obb   = (float*)alloc(128 * 4);
    float* dinv1 = (float*)alloc((size_t)NN * 4);
    float* dinv2 = (float*)alloc((size_t)NN * 4);
    u16*   src1p = (u16*)alloc((size_t)NN * 64 * 2);     // padded CSR, 64 u16 slots/node
    u16*   src2p = (u16*)alloc((size_t)NN * 64 * 2);
    int*   curz  = (int*)alloc((size_t)2 * NN * 4);      // cur1,cur2 (degree counters)
    float* bnsq  = (float*)alloc((size_t)LL * 16 * HH * 4);  // per layer: 8 sum + 8 sq bins
    float* wArr  = (float*)alloc(64);
    u16*   xb    = tb;            // x_bf16 dead once layer-0 conv GEMM writes tb

    int* cur1 = curz;

    hipMemsetAsync(curz, 0, (size_t)2 * NN * 4, stream);
    hipMemsetAsync(bnsq, 0, (size_t)LL * 16 * HH * 4, stream);

    // padded CSR build: XCD-partitioned (8 groups x 256 blocks), u16 slots
    k_fill2<<<8 * 256, 256, 0, stream>>>(e1, e2, curz, src1p, src2p);
    k_dinv2<<<(2 * NN + 255) / 256, 256, 0, stream>>>(curz, dinv1, dinv2, src1p, src2p, NN);

    k_softmaxw<<<1, 64, 0, stream>>>(lw, wArr);

    // weight prep
    {
        dim3 g(HH / 32, HH / 32, LL);
        dim3 b(32, 8);
        k_wt<<<g, b, 0, stream>>>(convW, convWt, HH, HH);
        dim3 g2(HH / 32, FIN / 32, 1);
        k_wt<<<g2, b, 0, stream>>>(inW, inWt, FIN, HH);
        k_outwt<<<128, 256, 0, stream>>>(outW, outb, outWt, obb);
    }
    k_xcast<<<(NN * FIN / 4 + 255) / 256, 256, 0, stream>>>(x, xb, NN * FIN / 4);

    const int MT = (NN + 127) / 128;               // 391
    const int GSW = ((MT + 7) / 8) * 16;           // swizzled grid: 784
    // input FC: hb = bf16( x @ inW + inb )   (standard layout: next GEMM's A)
    k_gemm_bf16<false, true, false, false><<<GSW, 256, 0, stream>>>(xb, inWt, inb, nullptr,
                                                                    hb, NN, HH, FIN);
    // zero the tb sentinel rows (after input FC: they alias the xb region before this point)
    k_zpad<<<1, 256, 0, stream>>>(tb);

    const int NBL = (NN + 127) / 128;              // 391 node-blocks (128 nodes each)
    const int SPB = NBL * NSL;                     // 391 x 8 slices = 3128 (% 8 == 0)
    const int ELB = (NN * (HH / 4) + 255) / 256;
    for (int i = 0; i < LL; ++i) {
        const int* dg = (i < LL / 2) ? cur1 : (curz + NN);
        const u16* sr = (i < LL / 2) ? src1p : src2p;
        const float* dv = (i < LL / 2) ? dinv1 : dinv2;
        float* bins = bnsq + (size_t)i * 16 * HH;
        // tb = bf16( dinv[r] * (hb @ convW_i + convB_i) )  in SLICED layout (stride SROW)
        k_gemm_bf16<false, true, true, false><<<GSW, 256, 0, stream>>>(hb,
                                                          convWt + (size_t)i * HH * HH,
                                                          convB + (size_t)i * HH, dv, tb,
                                                          NN, HH, HH);
        k_spmm_sl4<<<SPB, 512, 0, stream>>>(tb, dg, sr, dv, hpre, bins, bins + 8 * HH);
        k_bnnorm<<<ELB, 256, 0, stream>>>(hpre, accb, hb, bins,
                                          gamma + (size_t)i * HH, beta + (size_t)i * HH,
                                          wArr, i);
    }

    // out FC fused with log-softmax: d_out = log_softmax(accb @ outWt^T + obb)
    k_gemm_bf16<true, false, false, true><<<MT, 256, 0, stream>>>(accb, outWt, obb, nullptr,
                                                                  (float*)d_out, NN, CC, HH);
}

// Round 17
// 1077.419 us; speedup vs baseline: 1.3243x; 1.0039x over previous
//
#include <hip/hip_runtime.h>
#include <math.h>

#define NN 50000
#define HH 256
#define FIN 128
#define CC 112
#define LL 8
#define EE 800000
#define EPSB 1e-5f
#define NGRP 8
#define NPG (NN / NGRP)     // 6250 nodes per XCD-group
#define SLW 32              // spmm column-slice width (u16 -> 64 B/row = 1 line)
#define NSL (HH / SLW)      // 8 slices, one per XCD
#define SROW (NN + 1)       // sliced tb rows per slice: node rows + zero sentinel row NN

typedef unsigned short u16;
typedef unsigned int u32;
typedef __attribute__((ext_vector_type(8))) short bf16x8;
typedef __attribute__((ext_vector_type(4))) float f32x4;

__device__ __forceinline__ u16 f2bf(float f) {
    u32 u = __float_as_uint(f);
    u32 r = (u + 0x7FFFu + ((u >> 16) & 1u)) >> 16;   // RNE
    return (u16)r;
}
__device__ __forceinline__ float bflo(u32 u) { return __uint_as_float(u << 16); }
__device__ __forceinline__ float bfhi(u32 u) { return __uint_as_float(u & 0xFFFF0000u); }
__device__ __forceinline__ float bf1(u16 u) { return __uint_as_float(((u32)u) << 16); }

__device__ __forceinline__ void gload16(const u16* g, u16* l) {
    __builtin_amdgcn_global_load_lds(
        (const __attribute__((address_space(1))) void*)g,
        (__attribute__((address_space(3))) void*)l, 16, 0, 0);
}

// ---------------- padded CSR build, XCD-partitioned, UNROLL-4 atomic batching --------------
// Round-16 counters: VALU 5%, HBM 19%, occ 79% -> latency-bound on the single outstanding
// atomicAdd round-trip (~600-900 cy) per thread. Batch 4 edges: 4 predicated atomics issue
// back-to-back (4 concurrent round-trips) before the dependent stores wait.
__global__ __launch_bounds__(256) void k_fill2(const int* __restrict__ ed1,
                                               const int* __restrict__ ed2,
                                               int* __restrict__ cur,
                                               u16* __restrict__ src1p,
                                               u16* __restrict__ src2p) {
    const int g = blockIdx.x & 7;
    const int bg = blockIdx.x >> 3;
    const int nthr = (gridDim.x >> 3) * 256;
    const int tid = bg * 256 + threadIdx.x;
    const int lo = g * NPG;

    for (int e = tid; e < EE; e += 4 * nthr) {
        const int ea = e + nthr, eb = e + 2 * nthr, ec = e + 3 * nthr;
        int c0 = ed1[e + EE];
        int c1 = (ea < EE) ? ed1[ea + EE] : -1;
        int c2 = (eb < EE) ? ed1[eb + EE] : -1;
        int c3 = (ec < EE) ? ed1[ec + EE] : -1;
        const bool m0 = (u32)(c0 - lo) < (u32)NPG;
        const bool m1 = (u32)(c1 - lo) < (u32)NPG;
        const bool m2 = (u32)(c2 - lo) < (u32)NPG;
        const bool m3 = (u32)(c3 - lo) < (u32)NPG;
        int r0 = m0 ? ed1[e] : 0;
        int r1 = m1 ? ed1[ea] : 0;
        int r2 = m2 ? ed1[eb] : 0;
        int r3 = m3 ? ed1[ec] : 0;
        int p0 = m0 ? atomicAdd(&cur[c0], 1) : 0;
        int p1 = m1 ? atomicAdd(&cur[c1], 1) : 0;
        int p2 = m2 ? atomicAdd(&cur[c2], 1) : 0;
        int p3 = m3 ? atomicAdd(&cur[c3], 1) : 0;
        if (m0) src1p[(c0 << 6) + p0] = (u16)r0;
        if (m1) src1p[(c1 << 6) + p1] = (u16)r1;
        if (m2) src1p[(c2 << 6) + p2] = (u16)r2;
        if (m3) src1p[(c3 << 6) + p3] = (u16)r3;
    }
    for (int e = tid; e < EE; e += 4 * nthr) {
        const int ea = e + nthr, eb = e + 2 * nthr, ec = e + 3 * nthr;
        int c0 = ed2[e + EE];
        int c1 = (ea < EE) ? ed2[ea + EE] : -1;
        int c2 = (eb < EE) ? ed2[eb + EE] : -1;
        int c3 = (ec < EE) ? ed2[ec + EE] : -1;
        const bool m0 = (u32)(c0 - lo) < (u32)NPG;
        const bool m1 = (u32)(c1 - lo) < (u32)NPG;
        const bool m2 = (u32)(c2 - lo) < (u32)NPG;
        const bool m3 = (u32)(c3 - lo) < (u32)NPG;
        int r0 = m0 ? ed2[e] : 0;
        int r1 = m1 ? ed2[ea] : 0;
        int r2 = m2 ? ed2[eb] : 0;
        int r3 = m3 ? ed2[ec] : 0;
        int p0 = m0 ? atomicAdd(&cur[NN + c0], 1) : 0;
        int p1 = m1 ? atomicAdd(&cur[NN + c1], 1) : 0;
        int p2 = m2 ? atomicAdd(&cur[NN + c2], 1) : 0;
        int p3 = m3 ? atomicAdd(&cur[NN + c3], 1) : 0;
        if (m0) src2p[(c0 << 6) + p0] = (u16)r0;
        if (m1) src2p[(c1 << 6) + p1] = (u16)r1;
        if (m2) src2p[(c2 << 6) + p2] = (u16)r2;
        if (m3) src2p[(c3 << 6) + p3] = (u16)r3;
    }
}

// prep: dinv + srcp padding to mult-of-8 with sentinel NN; block 0 also zeroes the tb
// sentinel rows (tb no longer aliases xb) and computes the layer-weight softmax.
__global__ void k_prep(const int* __restrict__ deg, float* __restrict__ dinv1,
                       float* __restrict__ dinv2, u16* __restrict__ src1p,
                       u16* __restrict__ src2p, u16* __restrict__ tb,
                       const float* __restrict__ lw, float* __restrict__ wArr, int n) {
    if (blockIdx.x == 0) {
        int t = threadIdx.x;            // 256 = 8 slices x 32 cols
        int s = t >> 5, c = t & 31;
        tb[((size_t)s * SROW + NN) * SLW + c] = 0;
        if (t == 0) {
            float m = -3.0e38f;
            for (int i = 0; i < LL; ++i) m = fmaxf(m, lw[i]);
            float e[LL]; float sum = 0.f;
            for (int i = 0; i < LL; ++i) { e[i] = expf(lw[i] - m); sum += e[i]; }
            for (int i = 0; i < LL; ++i) wArr[i] = e[i] / sum;
        }
    }
    int v = blockIdx.x * blockDim.x + threadIdx.x;
    if (v >= 2 * n) return;
    int vv = (v < n) ? v : v - n;
    int dg = deg[v];
    ((v < n) ? dinv1 : dinv2)[vv] = rsqrtf((float)(dg + 1));  // +1 self-loop
    u16* sp = (v < n) ? src1p : src2p;
    int end8 = (dg + 7) & ~7;
    for (int j = dg; j < end8; ++j) sp[(vv << 6) + j] = (u16)NN;
}

// ---------------- weight transpose + bf16 cast: W[K][N] f32 -> Wt[N][K] bf16 ----------------
__global__ void k_wt(const float* __restrict__ W, u16* __restrict__ Wt, int K, int N) {
    __shared__ u16 sm[32][33];
    const float* Wl = W + (size_t)blockIdx.z * K * N;
    u16* Wtl = Wt + (size_t)blockIdx.z * K * N;
    int k0 = blockIdx.y * 32, n0 = blockIdx.x * 32;
    int tx = threadIdx.x, ty = threadIdx.y;  // 32 x 8
#pragma unroll
    for (int r = 0; r < 32; r += 8)
        sm[ty + r][tx] = f2bf(Wl[(size_t)(k0 + ty + r) * N + n0 + tx]);
    __syncthreads();
#pragma unroll
    for (int r = 0; r < 32; r += 8)
        Wtl[(size_t)(n0 + ty + r) * K + k0 + tx] = sm[tx][ty + r];
}

// outW [H=256][C=112] f32 -> outWt [128][256] bf16 (rows >= C zero); pad bias to 128
__global__ void k_outwt(const float* __restrict__ outW, const float* __restrict__ outb,
                        u16* __restrict__ outWt, float* __restrict__ obb) {
    int idx = blockIdx.x * 256 + threadIdx.x;     // 128*256
    if (idx >= 128 * 256) return;
    int n = idx >> 8, k = idx & 255;
    float v = (n < CC) ? outW[(size_t)k * CC + n] : 0.f;
    outWt[(size_t)n * HH + k] = f2bf(v);
    if (idx < 128) obb[idx] = (idx < CC) ? outb[idx] : 0.f;
}

// ---------------- fp32 -> bf16 cast ----------------
__global__ void k_xcast(const float* __restrict__ x, u16* __restrict__ xb, int n4) {
    int i = blockIdx.x * blockDim.x + threadIdx.x;
    if (i >= n4) return;
    float4 v = ((const float4*)x)[i];
    ushort4 o;
    o.x = f2bf(v.x); o.y = f2bf(v.y); o.z = f2bf(v.z); o.w = f2bf(v.w);
    *(ushort4*)(xb + ((size_t)i << 2)) = o;
}

// ---- bf16 MFMA GEMM: C = A @ Bt^T + bias, per-row scale; XCD-aware m/n swizzle when SWIZ ---
// SLICED: store u16 C in column-sliced layout [Nc/32][SROW][32] (stride M+1: sentinel row).
// LSM: fused log-softmax epilogue (out FC).
template <bool F32OUT, bool SWIZ, bool SLICED, bool LSM>
__global__ __launch_bounds__(256) void k_gemm_bf16(const u16* __restrict__ A,
                                                   const u16* __restrict__ Bt,
                                                   const float* __restrict__ bias,
                                                   const float* __restrict__ rowscale,
                                                   void* __restrict__ Cout,
                                                   int M, int Nc, int K) {
    int m0, n0;
    if (SWIZ) {
        int id = blockIdx.x;
        int g = id >> 4, r = id & 15;
        int m = g * 8 + (r & 7);
        if (m * 128 >= M) return;
        m0 = m * 128;
        n0 = (r >> 3) * 128;
    } else {
        m0 = blockIdx.x * 128;
        n0 = 0;
    }
    __shared__ u16 As[128 * 32];
    __shared__ u16 Bs[128 * 32];
    const int tid = threadIdx.x;
    const int w = tid >> 6, lane = tid & 63;
    const int wr = (w >> 1) * 64, wc = (w & 1) * 64;
    const int lm = lane & 15, lq = lane >> 4;

    f32x4 acc[4][4];
#pragma unroll
    for (int i = 0; i < 4; ++i)
#pragma unroll
        for (int j = 0; j < 4; ++j) acc[i][j] = (f32x4){0.f, 0.f, 0.f, 0.f};

    const int srow = w * 16 + (lane >> 2);
    const int scol = (lane & 3) * 8;

    for (int k0 = 0; k0 < K; k0 += 32) {
        int gm = m0 + srow;        if (gm >= M) gm = M - 1;
        gload16(A + (size_t)gm * K + k0 + scol, As + (size_t)(w * 64) * 8);
        int gm2 = m0 + 64 + srow;  if (gm2 >= M) gm2 = M - 1;
        gload16(A + (size_t)gm2 * K + k0 + scol, As + (size_t)(256 + w * 64) * 8);
        gload16(Bt + (size_t)(n0 + srow) * K + k0 + scol, Bs + (size_t)(w * 64) * 8);
        gload16(Bt + (size_t)(n0 + 64 + srow) * K + k0 + scol, Bs + (size_t)(256 + w * 64) * 8);
        __syncthreads();

        bf16x8 af[4], bfr[4];
#pragma unroll
        for (int i = 0; i < 4; ++i)
            af[i] = *(const bf16x8*)(As + (wr + i * 16 + lm) * 32 + lq * 8);
#pragma unroll
        for (int j = 0; j < 4; ++j)
            bfr[j] = *(const bf16x8*)(Bs + (wc + j * 16 + lm) * 32 + lq * 8);
#pragma unroll
        for (int i = 0; i < 4; ++i)
#pragma unroll
            for (int j = 0; j < 4; ++j)
                acc[i][j] = __builtin_amdgcn_mfma_f32_16x16x32_bf16(af[i], bfr[j], acc[i][j], 0, 0, 0);
        __syncthreads();
    }

    // epilogue: C/D layout col=lane&15, row=(lane>>4)*4+reg  [m89-verified]
    if (LSM) {
        __shared__ float smax[128][2];
        __shared__ float ssum[128][2];
        const int half = w & 1;
        float bj[4];
#pragma unroll
        for (int j = 0; j < 4; ++j) {
            int gc = wc + j * 16 + lm;
            bj[j] = (gc < Nc) ? bias[gc] : 0.f;
        }
#pragma unroll
        for (int i = 0; i < 4; ++i) {
#pragma unroll
            for (int r = 0; r < 4; ++r) {
                float m = -3.0e38f;
#pragma unroll
                for (int j = 0; j < 4; ++j) {
                    int gc = wc + j * 16 + lm;
                    if (gc < Nc) m = fmaxf(m, acc[i][j][r] + bj[j]);
                }
#pragma unroll
                for (int d = 1; d < 16; d <<= 1) m = fmaxf(m, __shfl_xor(m, d, 64));
                if (lm == 0) smax[wr + i * 16 + lq * 4 + r][half] = m;
            }
        }
        __syncthreads();
#pragma unroll
        for (int i = 0; i < 4; ++i) {
#pragma unroll
            for (int r = 0; r < 4; ++r) {
                int row = wr + i * 16 + lq * 4 + r;
                float rm = fmaxf(smax[row][0], smax[row][1]);
                float s = 0.f;
#pragma unroll
                for (int j = 0; j < 4; ++j) {
                    int gc = wc + j * 16 + lm;
                    if (gc < Nc) s += expf(acc[i][j][r] + bj[j] - rm);
                }
#pragma unroll
                for (int d = 1; d < 16; d <<= 1) s += __shfl_xor(s, d, 64);
                if (lm == 0) ssum[row][half] = s;
            }
        }
        __syncthreads();
#pragma unroll
        for (int i = 0; i < 4; ++i) {
#pragma unroll
            for (int r = 0; r < 4; ++r) {
                int row = wr + i * 16 + lq * 4 + r;
                int gr = m0 + row;
                if (gr < M) {
                    float rm = fmaxf(smax[row][0], smax[row][1]);
                    float lse = rm + logf(ssum[row][0] + ssum[row][1]);
#pragma unroll
                    for (int j = 0; j < 4; ++j) {
                        int gc = wc + j * 16 + lm;
                        if (gc < Nc)
                            ((float*)Cout)[(size_t)gr * Nc + gc] = acc[i][j][r] + bj[j] - lse;
                    }
                }
            }
        }
        return;
    }

#pragma unroll
    for (int j = 0; j < 4; ++j) {
        int gc = n0 + wc + j * 16 + lm;
        float bj = (gc < Nc) ? bias[gc] : 0.f;
#pragma unroll
        for (int i = 0; i < 4; ++i) {
#pragma unroll
            for (int r = 0; r < 4; ++r) {
                int gr = m0 + wr + i * 16 + lq * 4 + r;
                if (gr < M && gc < Nc) {
                    float rs = rowscale ? rowscale[gr] : 1.0f;
                    float val = (acc[i][j][r] + bj) * rs;
                    if (F32OUT)
                        ((float*)Cout)[(size_t)gr * Nc + gc] = val;
                    else if (SLICED)
                        ((u16*)Cout)[((size_t)(gc >> 5) * (M + 1) + gr) * SLW + (gc & 31)] = f2bf(val);
                    else
                        ((u16*)Cout)[(size_t)gr * Nc + gc] = f2bf(val);
                }
            }
        }
    }
}

#define ACC8(b) { A[0] += bflo(b.x); A[1] += bfhi(b.x); A[2] += bflo(b.y); A[3] += bfhi(b.y); \
                  A[4] += bflo(b.z); A[5] += bfhi(b.z); A[6] += bflo(b.w); A[7] += bfhi(b.w); }

// -- column-sliced gather SpMM, 4-lane row-subgroups, UNIFORM padded loop + fused BN stats ---
// slice = blockIdx & 7 -> pinned to one XCD (grid 3128 % 8 == 0). srcp lists padded to
// multiples of 8 with sentinel NN (zero row) -> single uniform unroll-8 loop, no tails.
__global__ __launch_bounds__(512) void k_spmm_sl4(const u16* __restrict__ ts,
                                                  const int* __restrict__ deg,
                                                  const u16* __restrict__ srcp,
                                                  const float* __restrict__ dinv,
                                                  u16* __restrict__ hpre,
                                                  float* __restrict__ bns,   // [8][HH]
                                                  float* __restrict__ bnq) { // [8][HH]
    __shared__ float lsum[8][SLW];
    __shared__ float lsq[8][SLW];
    const int s = blockIdx.x & 7;
    const int nb = blockIdx.x >> 3;
    const int w = threadIdx.x >> 6;
    const int lane = threadIdx.x & 63;
    const int sub = lane >> 2;          // node subgroup 0..15
    const int li = lane & 3;            // lane covers cols 8li..8li+7 of the slice (uint4)
    const u16* tsl = ts + (size_t)s * SROW * SLW + li * 8;

    const int v = nb * 128 + w * 16 + sub;
    float ss[8], qq[8];
#pragma unroll
    for (int k = 0; k < 8; ++k) { ss[k] = 0.f; qq[k] = 0.f; }

    if (v < NN) {
        const u16* src = srcp + ((size_t)v << 6);
        const float dv = dinv[v];
        uint4 a = *(const uint4*)(tsl + (size_t)v * SLW);
        float A[8];
        A[0] = bflo(a.x); A[1] = bfhi(a.x); A[2] = bflo(a.y); A[3] = bfhi(a.y);
        A[4] = bflo(a.z); A[5] = bfhi(a.z); A[6] = bflo(a.w); A[7] = bfhi(a.w);
        const int end = (deg[v] + 7) & ~7;       // padded: uniform 8-stride, no tails
        for (int j = 0; j < end; j += 8) {
            uint4 sp = *(const uint4*)(src + j);   // 8 packed u16 indices (subgroup-bcast)
            uint4 b0 = *(const uint4*)(tsl + (size_t)(sp.x & 0xFFFFu) * SLW);
            uint4 b1 = *(const uint4*)(tsl + (size_t)(sp.x >> 16) * SLW);
            uint4 b2 = *(const uint4*)(tsl + (size_t)(sp.y & 0xFFFFu) * SLW);
            uint4 b3 = *(const uint4*)(tsl + (size_t)(sp.y >> 16) * SLW);
            uint4 b4 = *(const uint4*)(tsl + (size_t)(sp.z & 0xFFFFu) * SLW);
            uint4 b5 = *(const uint4*)(tsl + (size_t)(sp.z >> 16) * SLW);
            uint4 b6 = *(const uint4*)(tsl + (size_t)(sp.w & 0xFFFFu) * SLW);
            uint4 b7 = *(const uint4*)(tsl + (size_t)(sp.w >> 16) * SLW);
            ACC8(b0); ACC8(b1); ACC8(b2); ACC8(b3);
            ACC8(b4); ACC8(b5); ACC8(b6); ACC8(b7);
        }
        u32 p01 = (u32)f2bf(A[0] * dv) | ((u32)f2bf(A[1] * dv) << 16);
        u32 p23 = (u32)f2bf(A[2] * dv) | ((u32)f2bf(A[3] * dv) << 16);
        u32 p45 = (u32)f2bf(A[4] * dv) | ((u32)f2bf(A[5] * dv) << 16);
        u32 p67 = (u32)f2bf(A[6] * dv) | ((u32)f2bf(A[7] * dv) << 16);
        uint4 ov; ov.x = p01; ov.y = p23; ov.z = p45; ov.w = p67;
        *(uint4*)(hpre + (size_t)v * HH + s * SLW + li * 8) = ov;
        ss[0] = bflo(p01); ss[1] = bfhi(p01); ss[2] = bflo(p23); ss[3] = bfhi(p23);
        ss[4] = bflo(p45); ss[5] = bfhi(p45); ss[6] = bflo(p67); ss[7] = bfhi(p67);
#pragma unroll
        for (int k = 0; k < 8; ++k) qq[k] = ss[k] * ss[k];
    }

    // reduce over the wave's 16 subgroups (lanes differing in bits 2..5)
#pragma unroll
    for (int d = 4; d < 64; d <<= 1) {
#pragma unroll
        for (int k = 0; k < 8; ++k) {
            ss[k] += __shfl_xor(ss[k], d, 64);
            qq[k] += __shfl_xor(qq[k], d, 64);
        }
    }
    if (lane < 4) {
#pragma unroll
        for (int k = 0; k < 8; ++k) { lsum[w][li * 8 + k] = ss[k]; lsq[w][li * 8 + k] = qq[k]; }
    }
    __syncthreads();
    int t = threadIdx.x;
    if (t < SLW) {
        float a = 0.f;
#pragma unroll
        for (int ww = 0; ww < 8; ++ww) a += lsum[ww][t];
        atomicAdd(&bns[(nb & 7) * HH + s * SLW + t], a);
    } else if (t < 2 * SLW) {
        int c = t - SLW;
        float a = 0.f;
#pragma unroll
        for (int ww = 0; ww < 8; ++ww) a += lsq[ww][c];
        atomicAdd(&bnq[(nb & 7) * HH + s * SLW + c], a);
    }
}

// ---- normalize + ReLU + weighted residual; bins folded once per block into LDS scale/shift -
// layer 0: accb implicitly zero (skip read; saves accb memset). layer LL-1: skip dead hb write.
__global__ __launch_bounds__(256) void k_bnnorm(const u16* __restrict__ hpre,
                         u16* __restrict__ accb, u16* __restrict__ hb,
                         const float* __restrict__ bins,   // [16][HH]: 8 sum + 8 sq
                         const float* __restrict__ gamma, const float* __restrict__ beta,
                         const float* __restrict__ wArr, int layer) {
    __shared__ float sscale[HH], sshift[HH];
    const float invN = 1.0f / (float)NN;
    {
        int tcol = threadIdx.x;
        float m = 0.f, qq = 0.f;
#pragma unroll
        for (int b = 0; b < 8; ++b) {
            m += bins[b * HH + tcol];
            qq += bins[(8 + b) * HH + tcol];
        }
        m *= invN;
        float var = qq * invN - m * m;
        float sc = rsqrtf(var + EPSB) * gamma[tcol];
        sscale[tcol] = sc;
        sshift[tcol] = beta[tcol] - m * sc;
    }
    __syncthreads();
    int idx = blockIdx.x * blockDim.x + threadIdx.x;
    if (idx >= NN * (HH / 4)) return;
    int c = (idx & 63) << 2;
    float w = wArr[layer];
    const bool first = (layer == 0);
    const bool last = (layer == LL - 1);
    ushort4 hv = ((const ushort4*)hpre)[idx];
    ushort4 av = make_ushort4(0, 0, 0, 0);
    if (!first) av = ((const ushort4*)accb)[idx];
    u16* hp = &hv.x;
    u16* ap = &av.x;
    ushort4 oh, oa;
    u16* ohp = &oh.x;
    u16* oap = &oa.x;
#pragma unroll
    for (int k = 0; k < 4; ++k) {
        float v = fmaf(bf1(hp[k]), sscale[c + k], sshift[c + k]);
        v = fmaxf(v, 0.f);
        oap[k] = f2bf(fmaf(w, v, bf1(ap[k])));
        ohp[k] = f2bf(v);
    }
    ((ushort4*)accb)[idx] = oa;
    if (!last) *(ushort4*)(hb + ((size_t)idx << 2)) = oh;
}

extern "C" void kernel_launch(void* const* d_in, const int* in_sizes, int n_in,
                              void* d_out, int out_size, void* d_ws, size_t ws_size,
                              hipStream_t stream) {
    const float* x     = (const float*)d_in[0];
    const int*   e1    = (const int*)d_in[1];
    const int*   e2    = (const int*)d_in[2];
    const float* inW   = (const float*)d_in[3];
    const float* inb   = (const float*)d_in[4];
    const float* convW = (const float*)d_in[5];
    const float* convB = (const float*)d_in[6];
    const float* gamma = (const float*)d_in[7];
    const float* beta  = (const float*)d_in[8];
    const float* outW  = (const float*)d_in[9];
    const float* outb  = (const float*)d_in[10];
    const float* lw    = (const float*)d_in[11];

    char* ws = (char*)d_ws;
    size_t off = 0;
    auto alloc = [&](size_t bytes) -> void* {
        void* p = ws + off;
        off = (off + bytes + 255) & ~(size_t)255;
        return p;
    };
    u16*   hb    = (u16*)alloc((size_t)NN * HH * 2);     // bf16 h (GEMM A)
    u16*   tb    = (u16*)alloc((size_t)SROW * HH * 2);   // bf16 t' SLICED [8][SROW][32]
    u16*   hpre  = (u16*)alloc((size_t)NN * HH * 2);     // spmm out; alias xb (free pre-spmm0)
    u16*   accb  = (u16*)alloc((size_t)NN * HH * 2);     // bf16 residual accumulator
    u16*   convWt= (u16*)alloc((size_t)LL * HH * HH * 2);
    u16*   inWt  = (u16*)alloc((size_t)HH * FIN * 2);
    u16*   outWt = (u16*)alloc((size_t)128 * HH * 2);
    float* obb   = (float*)alloc(128 * 4);
    float* dinv1 = (float*)alloc((size_t)NN * 4);
    float* dinv2 = (float*)alloc((size_t)NN * 4);
    u16*   src1p = (u16*)alloc((size_t)NN * 64 * 2);     // padded CSR, 64 u16 slots/node
    u16*   src2p = (u16*)alloc((size_t)NN * 64 * 2);
    int*   curz  = (int*)alloc((size_t)2 * NN * 4);      // cur1,cur2 (degree counters)
    float* bnsq  = (float*)alloc((size_t)LL * 16 * HH * 4);  // per layer: 8 sum + 8 sq bins
    float* wArr  = (float*)alloc(64);
    u16*   xb    = hpre;          // x_bf16 lives in hpre (free until spmm-0 writes it)

    int* cur1 = curz;

    hipMemsetAsync(curz, 0, (size_t)2 * NN * 4, stream);
    hipMemsetAsync(bnsq, 0, (size_t)LL * 16 * HH * 4, stream);

    // padded CSR build: XCD-partitioned (8 groups x 256 blocks), unroll-4 atomic batching
    k_fill2<<<8 * 256, 256, 0, stream>>>(e1, e2, curz, src1p, src2p);
    // prep: dinv + srcp padding + tb sentinel zero + layer-weight softmax
    k_prep<<<(2 * NN + 255) / 256, 256, 0, stream>>>(curz, dinv1, dinv2, src1p, src2p,
                                                     tb, lw, wArr, NN);

    // weight prep
    {
        dim3 g(HH / 32, HH / 32, LL);
        dim3 b(32, 8);
        k_wt<<<g, b, 0, stream>>>(convW, convWt, HH, HH);
        dim3 g2(HH / 32, FIN / 32, 1);
        k_wt<<<g2, b, 0, stream>>>(inW, inWt, FIN, HH);
        k_outwt<<<128, 256, 0, stream>>>(outW, outb, outWt, obb);
    }
    k_xcast<<<(NN * FIN / 4 + 255) / 256, 256, 0, stream>>>(x, xb, NN * FIN / 4);

    const int MT = (NN + 127) / 128;               // 391
    const int GSW = ((MT + 7) / 8) * 16;           // swizzled grid: 784
    // input FC: hb = bf16( x @ inW + inb )   (standard layout: next GEMM's A)
    k_gemm_bf16<false, true, false, false><<<GSW, 256, 0, stream>>>(xb, inWt, inb, nullptr,
                                                                    hb, NN, HH, FIN);

    const int NBL = (NN + 127) / 128;              // 391 node-blocks (128 nodes each)
    const int SPB = NBL * NSL;                     // 391 x 8 slices = 3128 (% 8 == 0)
    const int ELB = (NN * (HH / 4) + 255) / 256;
    for (int i = 0; i < LL; ++i) {
        const int* dg = (i < LL / 2) ? cur1 : (curz + NN);
        const u16* sr = (i < LL / 2) ? src1p : src2p;
        const float* dv = (i < LL / 2) ? dinv1 : dinv2;
        float* bins = bnsq + (size_t)i * 16 * HH;
        // tb = bf16( dinv[r] * (hb @ convW_i + convB_i) )  in SLICED layout (stride SROW)
        k_gemm_bf16<false, true, true, false><<<GSW, 256, 0, stream>>>(hb,
                                                          convWt + (size_t)i * HH * HH,
                                                          convB + (size_t)i * HH, dv, tb,
                                                          NN, HH, HH);
        k_spmm_sl4<<<SPB, 512, 0, stream>>>(tb, dg, sr, dv, hpre, bins, bins + 8 * HH);
        k_bnnorm<<<ELB, 256, 0, stream>>>(hpre, accb, hb, bins,
                                          gamma + (size_t)i * HH, beta + (size_t)i * HH,
                                          wArr, i);
    }

    // out FC fused with log-softmax: d_out = log_softmax(accb @ outWt^T + obb)
    k_gemm_bf16<true, false, false, true><<<MT, 256, 0, stream>>>(accb, outWt, obb, nullptr,
                                                                  (float*)d_out, NN, CC, HH);
}